// Round 2
// 3246.597 us; speedup vs baseline: 1.2006x; 1.2006x over previous
//
#include <hip/hip_runtime.h>
#include <cstdint>
#include <cstddef>

#define HDIM 1024
#define NE 4
#define NL 2
#define NHD 16
#define SEQ 512
#define BATCH 8
#define HFF 2816
#define KEEP 30
#define KEEPT (BATCH*KEEP)  // 240
#define TOK (BATCH*SEQ)   // 4096
#define MKP 256           // padded keep-rows (240 -> 256)
#define EPSV 1e-5f

typedef __bf16 bf16;
typedef bf16 bf16x8 __attribute__((ext_vector_type(8)));
typedef bf16 bf16x4 __attribute__((ext_vector_type(4)));
typedef float f32x4 __attribute__((ext_vector_type(4)));

__device__ __forceinline__ void gll16(const bf16* g, bf16* l) {
  __builtin_amdgcn_global_load_lds((const __attribute__((address_space(1))) void*)g,
                                   (__attribute__((address_space(3))) void*)l, 16, 0, 0);
}

// ---------------- concat pose|scene -> x [TOK, HDIM] ----------------
__global__ __launch_bounds__(256) void k_concat(const float* __restrict__ pose,
                                                const float* __restrict__ scene,
                                                float* __restrict__ x) {
  int idx4 = blockIdx.x * 256 + threadIdx.x;     // over TOK*HDIM/4 = 1048576
  int tok = idx4 >> 8;                           // HDIM/4 = 256 vec4 per token
  int c = (idx4 & 255) << 2;
  int b = tok >> 9, s = tok & 511;
  const float* src = (s < 256) ? (pose + ((size_t)(b*256 + s)*HDIM + c))
                               : (scene + ((size_t)(b*256 + (s-256))*HDIM + c));
  *(f32x4*)(x + (size_t)tok*HDIM + c) = *(const f32x4*)src;
}

// ---------------- router (only the 240 kept tokens) ----------------
__global__ __launch_bounds__(64) void k_router(const float* __restrict__ x,
                                               const float* __restrict__ w1, const float* __restrict__ b1,
                                               const float* __restrict__ w2, const float* __restrict__ b2,
                                               float* __restrict__ r) {
  int row = blockIdx.x;                 // b*KEEP + s
  int b = row / KEEP, s = row - b*KEEP;
  int lane = threadIdx.x;
  const float* xr = x + (size_t)(b*SEQ + s)*HDIM;
  float p0=0.f, p1=0.f, p2=0.f, p3=0.f;
  for (int k2 = lane; k2 < HDIM; k2 += 64) {
    float xv = xr[k2];
    const float* wr = w1 + k2*4;
    p0 += xv*wr[0]; p1 += xv*wr[1]; p2 += xv*wr[2]; p3 += xv*wr[3];
  }
  #pragma unroll
  for (int off = 32; off; off >>= 1) {
    p0 += __shfl_xor(p0, off); p1 += __shfl_xor(p1, off);
    p2 += __shfl_xor(p2, off); p3 += __shfl_xor(p3, off);
  }
  if (lane == 0) {
    float gg[4] = {p0 + b1[0], p1 + b1[1], p2 + b1[2], p3 + b1[3]};
    #pragma unroll
    for (int i = 0; i < 4; i++) gg[i] = 0.5f*gg[i]*(1.f + erff(gg[i]*0.70710678f));
    float rr[4], sum = 0.f;
    #pragma unroll
    for (int i = 0; i < 4; i++) {
      float a = b2[i];
      #pragma unroll
      for (int j = 0; j < 4; j++) a += gg[j]*w2[j*4 + i];
      rr[i] = 1.f/(1.f + __expf(-a));
      sum += rr[i];
    }
    float inv = 1.f / fmaxf(sum, 1e-8f);
    #pragma unroll
    for (int i = 0; i < 4; i++) r[row*4 + i] = rr[i]*inv;
  }
}

// ---------------- RMSNorm: fp32 in -> bf16 out ----------------
__global__ __launch_bounds__(256) void k_rmsnorm(const float* __restrict__ in,
                                                 const float* __restrict__ w,
                                                 bf16* __restrict__ out) {
  int row = blockIdx.x, tid = threadIdx.x;
  const float* xr = in + (size_t)row*HDIM;
  f32x4 v = *(const f32x4*)(xr + tid*4);
  float ss = v[0]*v[0] + v[1]*v[1] + v[2]*v[2] + v[3]*v[3];
  #pragma unroll
  for (int off = 32; off; off >>= 1) ss += __shfl_xor(ss, off);
  __shared__ float part[4];
  if ((tid & 63) == 0) part[tid >> 6] = ss;
  __syncthreads();
  float scale = rsqrtf((part[0]+part[1]+part[2]+part[3]) * (1.f/HDIM) + EPSV);
  f32x4 wv = *(const f32x4*)(w + tid*4);
  bf16x4 o;
  #pragma unroll
  for (int i = 0; i < 4; i++) o[i] = (bf16)(v[i]*scale*wv[i]);
  *(bf16x4*)(out + (size_t)row*HDIM + tid*4) = o;
}

// ------------- per-(e,l) weight convert: fp32 [K,N] -> bf16 [N,K] -------------
struct ConvArgs { const float* src[7]; bf16* dst[7]; };
__global__ __launch_bounds__(256) void k_convertT(ConvArgs a) {
  int id = blockIdx.x;   // 12544 tiles total
  int t, base;
  if (id < 4096)      { t = id >> 10; base = t << 10; }
  else if (id < 6912) { t = 4; base = 4096; }
  else if (id < 9728) { t = 5; base = 6912; }
  else                { t = 6; base = 9728; }
  int K = (t == 6) ? HFF : HDIM;
  int N = (t == 4 || t == 5) ? HFF : HDIM;
  int tl = id - base;
  int tilesN = N >> 5;
  int tk = tl / tilesN, tn = tl - tk*tilesN;
  __shared__ float tile[32][33];
  int tx = threadIdx.x & 31, ty = threadIdx.x >> 5;
  const float* src = a.src[t];
  bf16* dst = a.dst[t];
  #pragma unroll
  for (int i = 0; i < 4; i++) {
    int rr = ty + i*8;
    tile[rr][tx] = src[(size_t)(tk*32 + rr)*N + tn*32 + tx];
  }
  __syncthreads();
  #pragma unroll
  for (int i = 0; i < 4; i++) {
    int rr = ty + i*8;
    dst[(size_t)(tn*32 + rr)*K + tk*32 + tx] = (bf16)tile[tx][rr];
  }
}

// ---------------- bias pack: qkvb[el][0:1024|1024:2048|2048:3072] = wqb|wkb|wvb ----------------
__global__ __launch_bounds__(256) void k_pack_bias(const float* __restrict__ qb, const float* __restrict__ kb,
                                                   const float* __restrict__ vb, float* __restrict__ dst) {
  int idx = blockIdx.x*256 + threadIdx.x;  // 8*3072 = 24576
  int el = idx / 3072, j = idx - el*3072;
  float v = (j < 1024) ? qb[el*1024 + j]
          : (j < 2048) ? kb[el*1024 + j - 1024]
                       : vb[el*1024 + j - 2048];
  dst[idx] = v;
}

// ---------------- bf16 MFMA GEMM: C[M,N] = A[M,K] @ Bt[N,K]^T (+bias,+resid,*silu) ----------------
// m97 structure: 128x128 tile, BK=32, global_load_lds width-16 staging into LINEAR
// LDS [128][32] (no pad -- DMA dest is wave-uniform base + lane*16, pad would break it).
// grid = (N/128, M/128), block = 256 (4 waves, 2x2 of 64x64)
__global__ __launch_bounds__(256) void k_gemm(const bf16* __restrict__ A, const bf16* __restrict__ Bt,
    const float* __restrict__ bias, const float* __restrict__ resid, const bf16* __restrict__ siluSrc,
    float* __restrict__ outF, bf16* __restrict__ outB, int N, int K) {
  __shared__ bf16 As[128*32];
  __shared__ bf16 Bs[128*32];
  int tid = threadIdx.x;
  int wave = tid >> 6, lane = tid & 63;
  int quad = lane >> 4, l16 = lane & 15;
  int wm = (wave >> 1) * 64, wn = (wave & 1) * 64;
  int m0 = blockIdx.y * 128, n0 = blockIdx.x * 128;
  f32x4 zero4 = {0.f, 0.f, 0.f, 0.f};
  f32x4 acc[4][4];
  #pragma unroll
  for (int i = 0; i < 4; i++)
    #pragma unroll
    for (int j = 0; j < 4; j++) acc[i][j] = zero4;
  // staging: wave w covers rows w*32..w*32+31; issue0 = rows +0..15, issue1 = rows +16..31
  // lane l -> row (l>>2), col (l&3)*8  (16B per lane, 1KB per wave-issue, linear in LDS:
  // l*16B == ((l>>2)*32 + (l&3)*8) bf16 -> exactly row-major [row][col])
  int srow = wave*32 + (lane >> 2);
  int scol = (lane & 3) * 8;
  const bf16* Ap = A + (size_t)(m0 + srow)*K + scol;
  const bf16* Bp = Bt + (size_t)(n0 + srow)*K + scol;
  bf16* AsW = As + wave*1024;   // wave-uniform LDS base (elements)
  bf16* BsW = Bs + wave*1024;
  for (int k0 = 0; k0 < K; k0 += 32) {
    __syncthreads();                       // previous iter's ds_reads done
    gll16(Ap + k0,                AsW);
    gll16(Ap + k0 + (size_t)16*K, AsW + 512);
    gll16(Bp + k0,                BsW);
    gll16(Bp + k0 + (size_t)16*K, BsW + 512);
    __syncthreads();                       // vmcnt(0) drain -> LDS filled
    bf16x8 af[4], bq[4];
    #pragma unroll
    for (int i = 0; i < 4; i++) af[i] = *(const bf16x8*)&As[(wm + i*16 + l16)*32 + quad*8];
    #pragma unroll
    for (int i = 0; i < 4; i++) bq[i] = *(const bf16x8*)&Bs[(wn + i*16 + l16)*32 + quad*8];
    #pragma unroll
    for (int mi = 0; mi < 4; mi++)
      #pragma unroll
      for (int ni = 0; ni < 4; ni++)
        acc[mi][ni] = __builtin_amdgcn_mfma_f32_16x16x32_bf16(af[mi], bq[ni], acc[mi][ni], 0, 0, 0);
  }
  #pragma unroll
  for (int mi = 0; mi < 4; mi++) {
    #pragma unroll
    for (int ni = 0; ni < 4; ni++) {
      int colg = n0 + wn + ni*16 + l16;
      float bv = bias ? bias[colg] : 0.f;
      #pragma unroll
      for (int rr = 0; rr < 4; rr++) {
        int rowg = m0 + wm + mi*16 + quad*4 + rr;
        size_t off = (size_t)rowg*N + colg;
        float vv = acc[mi][ni][rr] + bv;
        if (resid) vv += resid[off];
        if (siluSrc) { float a = (float)siluSrc[off]; vv *= a / (1.f + __expf(-a)); }
        if (outF) outF[off] = vv;
        else      outB[off] = (bf16)vv;
      }
    }
  }
}

// ---------------- V transpose: vt[b][h][d][s] = v[(b*SEQ+s)*vs + h*64+d] ----------------
__global__ __launch_bounds__(256) void k_vtrans(const bf16* __restrict__ v, bf16* __restrict__ vt, int vs) {
  __shared__ bf16 t[64][72];
  int b = blockIdx.z, h = blockIdx.y, s0 = blockIdx.x * 64;
  int r = threadIdx.x >> 2, c0 = (threadIdx.x & 3) * 16;
  const bf16* vp = v + (size_t)(b*SEQ + s0 + r)*vs + h*64 + c0;
  bf16x8 v0 = *(const bf16x8*)vp;
  bf16x8 v1 = *(const bf16x8*)(vp + 8);
  #pragma unroll
  for (int j = 0; j < 8; j++) { t[r][c0+j] = v0[j]; t[r][c0+8+j] = v1[j]; }
  __syncthreads();
  bf16x8 o0, o1;
  #pragma unroll
  for (int j = 0; j < 8; j++) { o0[j] = t[c0+j][r]; o1[j] = t[c0+8+j][r]; }
  bf16* op = vt + ((size_t)(b*NHD + h)*64 + r)*512 + s0 + c0;
  *(bf16x8*)op = o0;
  *(bf16x8*)(op + 8) = o1;
}

// ---------------- MFMA attention ----------------
// grid (ceil(qlen/64), NH, B), block 256 = 4 waves; wave handles 16 q-rows x 512 keys.
// q/k are read from the fused QKV buffer with row stride qs.
// ALL loops touching acc[32] are FULLY unrolled — partial unroll demotes the
// 128-VGPR accumulator array to scratch (R1: 765 MB HBM spill traffic/dispatch).
__global__ __launch_bounds__(256, 1) void k_attn_mfma(const bf16* __restrict__ q,
    const bf16* __restrict__ k, const bf16* __restrict__ vt,
    bf16* __restrict__ o, int qlen, int orb, int qs) {
  __shared__ bf16 Ps[4][16][520];   // pad 8 keeps ds_read_b128 16B-aligned, 2-way row alias
  int tid = threadIdx.x;
  int wave = tid >> 6, lane = tid & 63;
  int quad = lane >> 4, l16 = lane & 15;
  int b = blockIdx.z, head = blockIdx.y;
  int q0 = blockIdx.x * 64 + wave * 16;

  const bf16* qp = q + (size_t)(b*SEQ + q0 + l16)*qs + head*64 + quad*8;
  bf16x8 aq0 = *(const bf16x8*)(qp);
  bf16x8 aq1 = *(const bf16x8*)(qp + 32);

  f32x4 z = {0.f, 0.f, 0.f, 0.f};
  f32x4 acc[32];
  #pragma unroll
  for (int ni = 0; ni < 32; ni++) acc[ni] = z;
  const bf16* kb = k + (size_t)(b*SEQ + l16)*qs + head*64 + quad*8;
  #pragma unroll
  for (int ni = 0; ni < 32; ni++) {
    const bf16* kp = kb + (size_t)(ni*16)*qs;
    bf16x8 b0 = *(const bf16x8*)(kp);
    bf16x8 b1 = *(const bf16x8*)(kp + 32);
    acc[ni] = __builtin_amdgcn_mfma_f32_16x16x32_bf16(aq0, b0, acc[ni], 0, 0, 0);
    acc[ni] = __builtin_amdgcn_mfma_f32_16x16x32_bf16(aq1, b1, acc[ni], 0, 0, 0);
  }
  // scale + row max (rows quad*4+rr live in the 16 lanes of this quad)
  float mx[4] = {-3e30f, -3e30f, -3e30f, -3e30f};
  #pragma unroll
  for (int ni = 0; ni < 32; ni++)
    #pragma unroll
    for (int rr = 0; rr < 4; rr++) {
      float s = acc[ni][rr] * 0.125f;
      acc[ni][rr] = s;
      mx[rr] = fmaxf(mx[rr], s);
    }
  #pragma unroll
  for (int off = 1; off <= 8; off <<= 1)
    #pragma unroll
    for (int rr = 0; rr < 4; rr++)
      mx[rr] = fmaxf(mx[rr], __shfl_xor(mx[rr], off));
  float sm[4] = {0.f, 0.f, 0.f, 0.f};
  #pragma unroll
  for (int ni = 0; ni < 32; ni++)
    #pragma unroll
    for (int rr = 0; rr < 4; rr++) {
      float p = __expf(acc[ni][rr] - mx[rr]);
      acc[ni][rr] = p;
      sm[rr] += p;
    }
  #pragma unroll
  for (int off = 1; off <= 8; off <<= 1)
    #pragma unroll
    for (int rr = 0; rr < 4; rr++)
      sm[rr] += __shfl_xor(sm[rr], off);
  // P (unnormalized) -> per-wave LDS slice in A-readable layout
  #pragma unroll
  for (int ni = 0; ni < 32; ni++)
    #pragma unroll
    for (int rr = 0; rr < 4; rr++)
      Ps[wave][quad*4 + rr][ni*16 + l16] = (bf16)acc[ni][rr];
  // PV
  const bf16* vtb = vt + ((size_t)(b*NHD + head)*64 + l16)*512 + quad*8;
  f32x4 accO[4] = {z, z, z, z};
  #pragma unroll 4
  for (int kk = 0; kk < 16; kk++) {
    bf16x8 ap = *(const bf16x8*)&Ps[wave][l16][kk*32 + quad*8];
    #pragma unroll
    for (int ni = 0; ni < 4; ni++) {
      bf16x8 bv = *(const bf16x8*)(vtb + (size_t)(ni*16)*512 + kk*32);
      accO[ni] = __builtin_amdgcn_mfma_f32_16x16x32_bf16(ap, bv, accO[ni], 0, 0, 0);
    }
  }
  float inv[4];
  #pragma unroll
  for (int rr = 0; rr < 4; rr++) inv[rr] = 1.f / sm[rr];
  #pragma unroll
  for (int ni = 0; ni < 4; ni++)
    #pragma unroll
    for (int rr = 0; rr < 4; rr++) {
      int row = q0 + quad*4 + rr;
      if (row < qlen)
        o[(size_t)(b*orb + row)*HDIM + head*64 + ni*16 + l16] = (bf16)(accO[ni][rr] * inv[rr]);
    }
}

// ---------------- gather kept rows of h -> hk (zero-pad 240..255), zero ok pad ----------------
__global__ __launch_bounds__(256) void k_gather(const float* __restrict__ h,
                                                float* __restrict__ hk, bf16* __restrict__ ok) {
  int idx = blockIdx.x*256 + threadIdx.x;    // 256*1024 = 262144
  int row = idx >> 10, col = idx & 1023;
  if (row < BATCH*KEEP) {
    int b = row / KEEP, s = row - b*KEEP;
    hk[idx] = h[(size_t)(b*SEQ + s)*HDIM + col];
  } else {
    hk[idx] = 0.f;
    ok[idx] = (bf16)0.f;
  }
}

// ---------------- combined += hk * r[:,e] ----------------
__global__ __launch_bounds__(256) void k_accum(float* __restrict__ comb, const float* __restrict__ hk,
                                               const float* __restrict__ r, int e, int first) {
  int idx = blockIdx.x*256 + threadIdx.x;    // 240*1024 = 245760
  int row = idx >> 10;
  float vv = hk[idx] * r[row*4 + e];
  comb[idx] = (first ? 0.f : comb[idx]) + vv;
}

// ---------------- final proj, split-K x16 with 8-row weight reuse ----------------
// grid (30, 16): block handles rows rg*8..+7, k-slice ks*64..+63.
// part[ks][row][1024] fp32 partials; k_ln reduces 16 slices + LayerNorm.
__global__ __launch_bounds__(256) void k_proj(const float* __restrict__ comb,
                                              const float* __restrict__ pw,
                                              float* __restrict__ part) {
  int rg = blockIdx.x, ks = blockIdx.y, tid = threadIdx.x;
  __shared__ float xr[8][64];
  for (int i = tid; i < 8*64; i += 256) {
    int r = i >> 6, kk = i & 63;
    xr[r][kk] = comb[(size_t)(rg*8 + r)*HDIM + ks*64 + kk];
  }
  __syncthreads();
  f32x4 acc[8];
  #pragma unroll
  for (int r = 0; r < 8; r++) acc[r] = (f32x4){0.f,0.f,0.f,0.f};
  const float* wp = pw + (size_t)(ks*64)*HDIM + tid*4;
  #pragma unroll 4
  for (int kk = 0; kk < 64; kk++) {
    f32x4 w4 = *(const f32x4*)(wp + (size_t)kk*HDIM);
    #pragma unroll
    for (int r = 0; r < 8; r++) acc[r] += xr[r][kk] * w4;
  }
  #pragma unroll
  for (int r = 0; r < 8; r++)
    *(f32x4*)(part + ((size_t)ks*KEEPT + rg*8 + r)*HDIM + tid*4) = acc[r];
}

__global__ __launch_bounds__(256) void k_ln(const float* __restrict__ part, const float* __restrict__ pb,
    const float* __restrict__ lnw, const float* __restrict__ lnb, float* __restrict__ out) {
  int row = blockIdx.x, tid = threadIdx.x;
  f32x4 acc = *(const f32x4*)(pb + tid*4);
  #pragma unroll
  for (int s = 0; s < 16; s++)
    acc += *(const f32x4*)(part + ((size_t)s*KEEPT + row)*HDIM + tid*4);
  float ps = acc[0]+acc[1]+acc[2]+acc[3];
  #pragma unroll
  for (int off = 32; off; off >>= 1) ps += __shfl_xor(ps, off);
  __shared__ float red1[4], red2[4];
  if ((tid & 63) == 0) red1[tid >> 6] = ps;
  __syncthreads();
  float mu = (red1[0]+red1[1]+red1[2]+red1[3]) * (1.f/HDIM);
  f32x4 d;
  #pragma unroll
  for (int i = 0; i < 4; i++) d[i] = acc[i] - mu;
  float pv = d[0]*d[0]+d[1]*d[1]+d[2]*d[2]+d[3]*d[3];
  #pragma unroll
  for (int off = 32; off; off >>= 1) pv += __shfl_xor(pv, off);
  if ((tid & 63) == 0) red2[tid >> 6] = pv;
  __syncthreads();
  float rs = rsqrtf((red2[0]+red2[1]+red2[2]+red2[3]) * (1.f/HDIM) + EPSV);
  f32x4 lw = *(const f32x4*)(lnw + tid*4);
  f32x4 lb = *(const f32x4*)(lnb + tid*4);
  f32x4 o;
  #pragma unroll
  for (int i = 0; i < 4; i++) o[i] = d[i]*rs*lw[i] + lb[i];
  *(f32x4*)(out + (size_t)row*HDIM + tid*4) = o;
}

extern "C" void kernel_launch(void* const* d_in, const int* in_sizes, int n_in,
                              void* d_out, int out_size, void* d_ws, size_t ws_size,
                              hipStream_t stream) {
  (void)in_sizes; (void)n_in; (void)out_size; (void)ws_size;
  const float* pose = (const float*)d_in[0];
  const float* scene = (const float*)d_in[1];
  const float* rf1w = (const float*)d_in[2];
  const float* rf1b = (const float*)d_in[3];
  const float* rf2w = (const float*)d_in[4];
  const float* rf2b = (const float*)d_in[5];
  const float* anw = (const float*)d_in[6];
  const float* wqw = (const float*)d_in[7];
  const float* wqb = (const float*)d_in[8];
  const float* wkw = (const float*)d_in[9];
  const float* wkb = (const float*)d_in[10];
  const float* wvw = (const float*)d_in[11];
  const float* wvb = (const float*)d_in[12];
  const float* wow = (const float*)d_in[13];
  const float* wob = (const float*)d_in[14];
  const float* fnw = (const float*)d_in[15];
  const float* w1w = (const float*)d_in[16];
  const float* w2w = (const float*)d_in[17];
  const float* w3w = (const float*)d_in[18];
  const float* pw  = (const float*)d_in[19];
  const float* pb  = (const float*)d_in[20];
  const float* lnw = (const float*)d_in[21];
  const float* lnb = (const float*)d_in[22];
  float* out = (float*)d_out;

  char* p = (char*)d_ws;
  auto carve = [&](size_t bytes) { void* r = (void*)p; p += (bytes + 255) & ~(size_t)255; return r; };
  // Footprint parity with the previously-passing kernel:
  //  qkv3 (24 MB) replaces qb_/kb_/vb_ (3x8 MB); qkvT (6 MB) replaces wqT/wkT/wvT (3x2 MB);
  //  part (15.7 MB) ALIASES a1 (23 MB, dead after the expert loop — last read is the
  //  l=1,e=3 w3-GEMM's siluSrc; k_proj runs strictly after). Net delta vs old: +qkvb 0.1 MB.
  float* x   = (float*)carve((size_t)TOK*HDIM*4);
  float* h   = (float*)carve((size_t)TOK*HDIM*4);
  bf16* xn   = (bf16*)carve((size_t)TOK*HDIM*2);
  bf16* qkv3 = (bf16*)carve((size_t)TOK*3072*2);     // fused Q|K|V, row stride 3072
  bf16* ob_  = (bf16*)carve((size_t)TOK*HDIM*2);
  bf16* vt   = (bf16*)carve((size_t)TOK*HDIM*2);     // vt[b][h][64][512]
  bf16* a1   = (bf16*)carve((size_t)TOK*HFF*2);
  bf16* g    = (bf16*)carve((size_t)TOK*HFF*2);
  bf16* qkvT = (bf16*)carve((size_t)3072*HDIM*2);    // stacked wq^T|wk^T|wv^T [3072][1024]
  bf16* woT  = (bf16*)carve((size_t)HDIM*HDIM*2);
  bf16* w1T  = (bf16*)carve((size_t)HDIM*HFF*2);
  bf16* w3T  = (bf16*)carve((size_t)HDIM*HFF*2);
  bf16* w2T  = (bf16*)carve((size_t)HFF*HDIM*2);
  float* hk  = (float*)carve((size_t)MKP*HDIM*4);
  bf16* hnk  = (bf16*)carve((size_t)MKP*HDIM*2);
  bf16* okb  = (bf16*)carve((size_t)MKP*HDIM*2);
  float* comb = (float*)carve((size_t)KEEPT*HDIM*4);
  float* rbuf = (float*)carve((size_t)KEEPT*4*4);
  float* qkvb = (float*)carve((size_t)8*3072*4);     // packed per-(e,l) qkv biases
  float* part = (float*)a1;                          // alias: 16*KEEPT*HDIM*4 = 15.7 MB <= 23 MB

  k_concat<<<4096, 256, 0, stream>>>(pose, scene, x);
  k_router<<<KEEPT, 64, 0, stream>>>(x, rf1w, rf1b, rf2w, rf2b, rbuf);
  k_pack_bias<<<96, 256, 0, stream>>>(wqb, wkb, wvb, qkvb);

  for (int e = 0; e < NE; e++) {
    for (int l = 0; l < NL; l++) {
      int el = e*NL + l;
      ConvArgs ca;
      ca.src[0] = wqw + (size_t)el*HDIM*HDIM;
      ca.src[1] = wkw + (size_t)el*HDIM*HDIM;
      ca.src[2] = wvw + (size_t)el*HDIM*HDIM;
      ca.src[3] = wow + (size_t)el*HDIM*HDIM;
      ca.src[4] = w1w + (size_t)el*HDIM*HFF;
      ca.src[5] = w3w + (size_t)el*HDIM*HFF;
      ca.src[6] = w2w + (size_t)el*HFF*HDIM;
      ca.dst[0] = qkvT;
      ca.dst[1] = qkvT + (size_t)1024*HDIM;
      ca.dst[2] = qkvT + (size_t)2048*HDIM;
      ca.dst[3] = woT;
      ca.dst[4] = w1T; ca.dst[5] = w3T; ca.dst[6] = w2T;
      k_convertT<<<12544, 256, 0, stream>>>(ca);

      const float* src_h = (l == 0) ? x : h;
      k_rmsnorm<<<TOK, 256, 0, stream>>>(src_h, anw + (size_t)el*HDIM, xn);
      // fused QKV GEMM: [4096,1024] @ [3072,1024]^T -> [4096,3072]
      k_gemm<<<dim3(24, 32), 256, 0, stream>>>(xn, qkvT, qkvb + (size_t)el*3072,
                                               nullptr, nullptr, nullptr, qkv3, 3072, HDIM);
      k_vtrans<<<dim3(8, NHD, BATCH), 256, 0, stream>>>(qkv3 + 2048, vt, 3072);

      if (l == 0) {
        k_attn_mfma<<<dim3(8, NHD, BATCH), 256, 0, stream>>>(qkv3, qkv3 + 1024, vt, ob_, SEQ, SEQ, 3072);
        k_gemm<<<dim3(8, 32), 256, 0, stream>>>(ob_, woT, wob + (size_t)el*HDIM, x, nullptr, h, nullptr, HDIM, HDIM);
        k_rmsnorm<<<TOK, 256, 0, stream>>>(h, fnw + (size_t)el*HDIM, xn);
        k_gemm<<<dim3(22, 32), 256, 0, stream>>>(xn, w1T, nullptr, nullptr, nullptr, nullptr, a1, HFF, HDIM);
        k_gemm<<<dim3(22, 32), 256, 0, stream>>>(xn, w3T, nullptr, nullptr, a1, nullptr, g, HFF, HDIM);
        k_gemm<<<dim3(8, 32), 256, 0, stream>>>(g, w2T, nullptr, h, nullptr, h, nullptr, HDIM, HFF);
      } else {
        k_attn_mfma<<<dim3(1, NHD, BATCH), 256, 0, stream>>>(qkv3, qkv3 + 1024, vt, okb, KEEP, KEEP, 3072);
        k_gather<<<1024, 256, 0, stream>>>(h, hk, okb);
        k_gemm<<<dim3(8, 2), 256, 0, stream>>>(okb, woT, wob + (size_t)el*HDIM, hk, nullptr, hk, nullptr, HDIM, HDIM);
        k_rmsnorm<<<MKP, 256, 0, stream>>>(hk, fnw + (size_t)el*HDIM, hnk);
        k_gemm<<<dim3(22, 2), 256, 0, stream>>>(hnk, w1T, nullptr, nullptr, nullptr, nullptr, a1, HFF, HDIM);
        k_gemm<<<dim3(22, 2), 256, 0, stream>>>(hnk, w3T, nullptr, nullptr, a1, nullptr, g, HFF, HDIM);
        k_gemm<<<dim3(8, 2), 256, 0, stream>>>(g, w2T, nullptr, hk, nullptr, hk, nullptr, HDIM, HFF);
        k_accum<<<960, 256, 0, stream>>>(comb, hk, rbuf, e, (e == 0) ? 1 : 0);
      }
    }
  }
  k_proj<<<dim3(30, 16), 256, 0, stream>>>(comb, pw, part);
  k_ln<<<KEEPT, 256, 0, stream>>>(part, pb, lnw, lnb, out);
}

// Round 3
// 2872.180 us; speedup vs baseline: 1.3571x; 1.1304x over previous
//
#include <hip/hip_runtime.h>
#include <cstdint>
#include <cstddef>

#define HDIM 1024
#define NE 4
#define NL 2
#define NHD 16
#define SEQ 512
#define BATCH 8
#define HFF 2816
#define KEEP 30
#define KEEPT (BATCH*KEEP)  // 240
#define TOK (BATCH*SEQ)   // 4096
#define MKP 256           // padded keep-rows (240 -> 256)
#define EPSV 1e-5f

typedef __bf16 bf16;
typedef bf16 bf16x8 __attribute__((ext_vector_type(8)));
typedef bf16 bf16x4 __attribute__((ext_vector_type(4)));
typedef float f32x4 __attribute__((ext_vector_type(4)));

__device__ __forceinline__ void gll16(const bf16* g, bf16* l) {
  __builtin_amdgcn_global_load_lds((const __attribute__((address_space(1))) void*)g,
                                   (__attribute__((address_space(3))) void*)l, 16, 0, 0);
}

// ---------------- concat pose|scene -> x [TOK, HDIM] ----------------
__global__ __launch_bounds__(256) void k_concat(const float* __restrict__ pose,
                                                const float* __restrict__ scene,
                                                float* __restrict__ x) {
  int idx4 = blockIdx.x * 256 + threadIdx.x;     // over TOK*HDIM/4 = 1048576
  int tok = idx4 >> 8;                           // HDIM/4 = 256 vec4 per token
  int c = (idx4 & 255) << 2;
  int b = tok >> 9, s = tok & 511;
  const float* src = (s < 256) ? (pose + ((size_t)(b*256 + s)*HDIM + c))
                               : (scene + ((size_t)(b*256 + (s-256))*HDIM + c));
  *(f32x4*)(x + (size_t)tok*HDIM + c) = *(const f32x4*)src;
}

// ---------------- router (only the 240 kept tokens) ----------------
__global__ __launch_bounds__(64) void k_router(const float* __restrict__ x,
                                               const float* __restrict__ w1, const float* __restrict__ b1,
                                               const float* __restrict__ w2, const float* __restrict__ b2,
                                               float* __restrict__ r) {
  int row = blockIdx.x;                 // b*KEEP + s
  int b = row / KEEP, s = row - b*KEEP;
  int lane = threadIdx.x;
  const float* xr = x + (size_t)(b*SEQ + s)*HDIM;
  float p0=0.f, p1=0.f, p2=0.f, p3=0.f;
  for (int k2 = lane; k2 < HDIM; k2 += 64) {
    float xv = xr[k2];
    const float* wr = w1 + k2*4;
    p0 += xv*wr[0]; p1 += xv*wr[1]; p2 += xv*wr[2]; p3 += xv*wr[3];
  }
  #pragma unroll
  for (int off = 32; off; off >>= 1) {
    p0 += __shfl_xor(p0, off); p1 += __shfl_xor(p1, off);
    p2 += __shfl_xor(p2, off); p3 += __shfl_xor(p3, off);
  }
  if (lane == 0) {
    float gg[4] = {p0 + b1[0], p1 + b1[1], p2 + b1[2], p3 + b1[3]};
    #pragma unroll
    for (int i = 0; i < 4; i++) gg[i] = 0.5f*gg[i]*(1.f + erff(gg[i]*0.70710678f));
    float rr[4], sum = 0.f;
    #pragma unroll
    for (int i = 0; i < 4; i++) {
      float a = b2[i];
      #pragma unroll
      for (int j = 0; j < 4; j++) a += gg[j]*w2[j*4 + i];
      rr[i] = 1.f/(1.f + __expf(-a));
      sum += rr[i];
    }
    float inv = 1.f / fmaxf(sum, 1e-8f);
    #pragma unroll
    for (int i = 0; i < 4; i++) r[row*4 + i] = rr[i]*inv;
  }
}

// ---------------- RMSNorm: fp32 in -> bf16 out ----------------
__global__ __launch_bounds__(256) void k_rmsnorm(const float* __restrict__ in,
                                                 const float* __restrict__ w,
                                                 bf16* __restrict__ out) {
  int row = blockIdx.x, tid = threadIdx.x;
  const float* xr = in + (size_t)row*HDIM;
  f32x4 v = *(const f32x4*)(xr + tid*4);
  float ss = v[0]*v[0] + v[1]*v[1] + v[2]*v[2] + v[3]*v[3];
  #pragma unroll
  for (int off = 32; off; off >>= 1) ss += __shfl_xor(ss, off);
  __shared__ float part[4];
  if ((tid & 63) == 0) part[tid >> 6] = ss;
  __syncthreads();
  float scale = rsqrtf((part[0]+part[1]+part[2]+part[3]) * (1.f/HDIM) + EPSV);
  f32x4 wv = *(const f32x4*)(w + tid*4);
  bf16x4 o;
  #pragma unroll
  for (int i = 0; i < 4; i++) o[i] = (bf16)(v[i]*scale*wv[i]);
  *(bf16x4*)(out + (size_t)row*HDIM + tid*4) = o;
}

// ------------- per-(e,l) weight convert: fp32 [K,N] -> bf16 [N,K] -------------
// t=4 (w1) / t=5 (w3) write into ONE stacked buffer with 16-column interleave:
// dest row for source col gr:  (gr>>4)*32 + (t==5 ? 16 : 0) + (gr&15)
// so the fused w13 GEMM's wave holds matching silu pairs in adjacent ni slots.
struct ConvArgs { const float* src[7]; bf16* dst[7]; };
__global__ __launch_bounds__(256) void k_convertT(ConvArgs a) {
  int id = blockIdx.x;   // 12544 tiles total
  int t, base;
  if (id < 4096)      { t = id >> 10; base = t << 10; }
  else if (id < 6912) { t = 4; base = 4096; }
  else if (id < 9728) { t = 5; base = 6912; }
  else                { t = 6; base = 9728; }
  int K = (t == 6) ? HFF : HDIM;
  int N = (t == 4 || t == 5) ? HFF : HDIM;
  int tl = id - base;
  int tilesN = N >> 5;
  int tk = tl / tilesN, tn = tl - tk*tilesN;
  __shared__ float tile[32][33];
  int tx = threadIdx.x & 31, ty = threadIdx.x >> 5;
  const float* src = a.src[t];
  bf16* dst = a.dst[t];
  #pragma unroll
  for (int i = 0; i < 4; i++) {
    int rr = ty + i*8;
    tile[rr][tx] = src[(size_t)(tk*32 + rr)*N + tn*32 + tx];
  }
  __syncthreads();
  #pragma unroll
  for (int i = 0; i < 4; i++) {
    int rr = ty + i*8;
    int gr = tn*32 + rr;
    size_t dr;
    if (t == 4)      dr = (size_t)((gr >> 4)*32 + (gr & 15));
    else if (t == 5) dr = (size_t)((gr >> 4)*32 + 16 + (gr & 15));
    else             dr = (size_t)gr;
    dst[dr*K + tk*32 + tx] = (bf16)tile[tx][rr];
  }
}

// ---------------- bias pack: qkvb[el][0:1024|1024:2048|2048:3072] = wqb|wkb|wvb ----------------
__global__ __launch_bounds__(256) void k_pack_bias(const float* __restrict__ qb, const float* __restrict__ kb,
                                                   const float* __restrict__ vb, float* __restrict__ dst) {
  int idx = blockIdx.x*256 + threadIdx.x;  // 8*3072 = 24576
  int el = idx / 3072, j = idx - el*3072;
  float v = (j < 1024) ? qb[el*1024 + j]
          : (j < 2048) ? kb[el*1024 + j - 1024]
                       : vb[el*1024 + j - 2048];
  dst[idx] = v;
}

// ---------------- 128x128 bf16 MFMA GEMM (2-barrier, gll staging) ----------------
// kept for wo / w2 / small l=1 GEMMs (grids where 256^2 would under-fill CUs)
__global__ __launch_bounds__(256) void k_gemm(const bf16* __restrict__ A, const bf16* __restrict__ Bt,
    const float* __restrict__ bias, const float* __restrict__ resid, const bf16* __restrict__ siluSrc,
    float* __restrict__ outF, bf16* __restrict__ outB, int N, int K) {
  __shared__ bf16 As[128*32];
  __shared__ bf16 Bs[128*32];
  int tid = threadIdx.x;
  int wave = tid >> 6, lane = tid & 63;
  int quad = lane >> 4, l16 = lane & 15;
  int wm = (wave >> 1) * 64, wn = (wave & 1) * 64;
  int m0 = blockIdx.y * 128, n0 = blockIdx.x * 128;
  f32x4 zero4 = {0.f, 0.f, 0.f, 0.f};
  f32x4 acc[4][4];
  #pragma unroll
  for (int i = 0; i < 4; i++)
    #pragma unroll
    for (int j = 0; j < 4; j++) acc[i][j] = zero4;
  int srow = wave*32 + (lane >> 2);
  int scol = (lane & 3) * 8;
  const bf16* Ap = A + (size_t)(m0 + srow)*K + scol;
  const bf16* Bp = Bt + (size_t)(n0 + srow)*K + scol;
  bf16* AsW = As + wave*1024;   // wave-uniform LDS base (elements)
  bf16* BsW = Bs + wave*1024;
  for (int k0 = 0; k0 < K; k0 += 32) {
    __syncthreads();
    gll16(Ap + k0,                AsW);
    gll16(Ap + k0 + (size_t)16*K, AsW + 512);
    gll16(Bp + k0,                BsW);
    gll16(Bp + k0 + (size_t)16*K, BsW + 512);
    __syncthreads();
    bf16x8 af[4], bq[4];
    #pragma unroll
    for (int i = 0; i < 4; i++) af[i] = *(const bf16x8*)&As[(wm + i*16 + l16)*32 + quad*8];
    #pragma unroll
    for (int i = 0; i < 4; i++) bq[i] = *(const bf16x8*)&Bs[(wn + i*16 + l16)*32 + quad*8];
    #pragma unroll
    for (int mi = 0; mi < 4; mi++)
      #pragma unroll
      for (int ni = 0; ni < 4; ni++)
        acc[mi][ni] = __builtin_amdgcn_mfma_f32_16x16x32_bf16(af[mi], bq[ni], acc[mi][ni], 0, 0, 0);
  }
  #pragma unroll
  for (int mi = 0; mi < 4; mi++) {
    #pragma unroll
    for (int ni = 0; ni < 4; ni++) {
      int colg = n0 + wn + ni*16 + l16;
      float bv = bias ? bias[colg] : 0.f;
      #pragma unroll
      for (int rr = 0; rr < 4; rr++) {
        int rowg = m0 + wm + mi*16 + quad*4 + rr;
        size_t off = (size_t)rowg*N + colg;
        float vv = acc[mi][ni][rr] + bv;
        if (resid) vv += resid[off];
        if (siluSrc) { float a = (float)siluSrc[off]; vv *= a / (1.f + __expf(-a)); }
        if (outF) outF[off] = vv;
        else      outB[off] = (bf16)vv;
      }
    }
  }
}

// ---------------- 256x256 counted-vmcnt phase GEMM (T3+T4+T5, plain HIP) ----------------
// 512 thr = 8 waves (2M x 4N), per-wave C = 128x64 (acc[8][4]); BK=32, LDS dbuf 64 KB.
// Staged 2 K-tiles ahead via global_load_lds; vmcnt(4) counted waits (never 0 in loop);
// raw s_barrier via asm (NO __syncthreads -> no vmcnt(0) drain). Buffer for kt+2 is
// written only after phase-1's post-MFMA barrier (all waves' lgkmcnt(0) passed -> all
// reads of that buffer complete). swiglu=1: Bt is 16-col-interleaved w1|w3, epilogue
// writes g = silu(a1)*a3 with stride N/2 (no intermediate buffer).
__global__ __launch_bounds__(512, 2) void k_gemm256(const bf16* __restrict__ A, const bf16* __restrict__ Bt,
    const float* __restrict__ bias, bf16* __restrict__ out, int N, int K, int swiglu) {
  __shared__ __align__(16) bf16 As[2][256*32];
  __shared__ __align__(16) bf16 Bs[2][256*32];
  int tid = threadIdx.x;
  int wave = tid >> 6, lane = tid & 63;
  int quad = lane >> 4, l16 = lane & 15;
  int wm128 = (wave >> 2) * 128;       // 2 waves in M
  int wn64  = (wave & 3) * 64;         // 4 waves in N
  int m0 = blockIdx.y * 256, n0 = blockIdx.x * 256;
  int NT = K >> 5;
  f32x4 z = {0.f, 0.f, 0.f, 0.f};
  f32x4 acc[8][4];
  #pragma unroll
  for (int i = 0; i < 8; i++)
    #pragma unroll
    for (int j = 0; j < 4; j++) acc[i][j] = z;
  // staging: per round r (2 rounds/matrix/K-tile), wave w covers rows r*128 + w*16 + (lane>>2),
  // granule (lane&3)*8 elems; LDS dest wave-uniform base + lane*16B == row-major linear.
  const bf16* aSrc = A + (size_t)(m0 + wave*16 + (lane>>2))*K + (lane&3)*8;
  const bf16* bSrc = Bt + (size_t)(n0 + wave*16 + (lane>>2))*K + (lane&3)*8;
  auto stage = [&](int buf, int kt) {
    #pragma unroll
    for (int r = 0; r < 2; r++) {
      gll16(aSrc + (size_t)(r*128)*K + kt*32, &As[buf][(r*128 + wave*16)*32]);
      gll16(bSrc + (size_t)(r*128)*K + kt*32, &Bs[buf][(r*128 + wave*16)*32]);
    }
  };
  stage(0, 0);
  stage(1, 1);
  asm volatile("s_waitcnt vmcnt(4)" ::: "memory");   // tile 0 landed (mine); barrier -> all
  asm volatile("s_barrier" ::: "memory");
  for (int kt = 0; kt < NT; ++kt) {
    int cur = kt & 1;
    bf16x8 pb[4];
    // ---- phase 0: C rows wm128+0..63 ----
    {
      bf16x8 pa[4];
      #pragma unroll
      for (int i = 0; i < 4; i++)
        pa[i] = *(const bf16x8*)&As[cur][(wm128 + i*16 + l16)*32 + quad*8];
      #pragma unroll
      for (int i = 0; i < 4; i++)
        pb[i] = *(const bf16x8*)&Bs[cur][(wn64 + i*16 + l16)*32 + quad*8];
      asm volatile("s_barrier" ::: "memory");
      __builtin_amdgcn_s_setprio(1);
      #pragma unroll
      for (int mi = 0; mi < 4; mi++)
        #pragma unroll
        for (int ni = 0; ni < 4; ni++)
          acc[mi][ni] = __builtin_amdgcn_mfma_f32_16x16x32_bf16(pa[mi], pb[ni], acc[mi][ni], 0, 0, 0);
      __builtin_amdgcn_s_setprio(0);
      asm volatile("s_barrier" ::: "memory");
    }
    // ---- phase 1: C rows wm128+64..127 ----
    {
      bf16x8 pa[4];
      #pragma unroll
      for (int i = 0; i < 4; i++)
        pa[i] = *(const bf16x8*)&As[cur][(wm128 + 64 + i*16 + l16)*32 + quad*8];
      asm volatile("s_barrier" ::: "memory");
      __builtin_amdgcn_s_setprio(1);
      #pragma unroll
      for (int mi = 0; mi < 4; mi++)
        #pragma unroll
        for (int ni = 0; ni < 4; ni++)
          acc[4+mi][ni] = __builtin_amdgcn_mfma_f32_16x16x32_bf16(pa[mi], pb[ni], acc[4+mi][ni], 0, 0, 0);
      __builtin_amdgcn_s_setprio(0);
      asm volatile("s_barrier" ::: "memory");   // all waves done reading buf[cur]
    }
    if (kt + 1 < NT) {
      if (kt + 2 < NT) {
        stage(cur, kt + 2);                     // overwrite freed buffer; lands over next iter
        asm volatile("s_waitcnt vmcnt(4)" ::: "memory");  // tile kt+1 complete, kt+2 in flight
      } else {
        asm volatile("s_waitcnt vmcnt(0)" ::: "memory");  // last tile (issued long ago)
      }
      asm volatile("s_barrier" ::: "memory");
    }
  }
  // ---- epilogue (proven C layout: row = quad*4+rr, col = l16) ----
  if (!swiglu) {
    #pragma unroll
    for (int ni = 0; ni < 4; ni++) {
      int colg = n0 + wn64 + ni*16 + l16;
      float bv = bias ? bias[colg] : 0.f;
      #pragma unroll
      for (int mi = 0; mi < 8; mi++)
        #pragma unroll
        for (int rr = 0; rr < 4; rr++) {
          int rowg = m0 + wm128 + mi*16 + quad*4 + rr;
          out[(size_t)rowg*N + colg] = (bf16)(acc[mi][ni][rr] + bv);
        }
    }
  } else {
    int half = N >> 1;
    #pragma unroll
    for (int np = 0; np < 2; np++) {
      int colo = ((n0 + wn64) >> 1) + np*16 + l16;
      #pragma unroll
      for (int mi = 0; mi < 8; mi++)
        #pragma unroll
        for (int rr = 0; rr < 4; rr++) {
          int rowg = m0 + wm128 + mi*16 + quad*4 + rr;
          float xv = acc[mi][np*2][rr];
          float yv = acc[mi][np*2+1][rr];
          out[(size_t)rowg*half + colo] = (bf16)(xv / (1.f + __expf(-xv)) * yv);
        }
    }
  }
}

// ---------------- V transpose: vt[b][h][d][s] = v[(b*SEQ+s)*vs + h*64+d] ----------------
__global__ __launch_bounds__(256) void k_vtrans(const bf16* __restrict__ v, bf16* __restrict__ vt, int vs) {
  __shared__ bf16 t[64][72];
  int b = blockIdx.z, h = blockIdx.y, s0 = blockIdx.x * 64;
  int r = threadIdx.x >> 2, c0 = (threadIdx.x & 3) * 16;
  const bf16* vp = v + (size_t)(b*SEQ + s0 + r)*vs + h*64 + c0;
  bf16x8 v0 = *(const bf16x8*)vp;
  bf16x8 v1 = *(const bf16x8*)(vp + 8);
  #pragma unroll
  for (int j = 0; j < 8; j++) { t[r][c0+j] = v0[j]; t[r][c0+8+j] = v1[j]; }
  __syncthreads();
  bf16x8 o0, o1;
  #pragma unroll
  for (int j = 0; j < 8; j++) { o0[j] = t[c0+j][r]; o1[j] = t[c0+8+j][r]; }
  bf16* op = vt + ((size_t)(b*NHD + h)*64 + r)*512 + s0 + c0;
  *(bf16x8*)op = o0;
  *(bf16x8*)(op + 8) = o1;
}

// ---------------- MFMA attention ----------------
// ALL loops touching acc[32] are FULLY unrolled — partial unroll demotes the
// 128-VGPR accumulator array to scratch (R1: 765 MB HBM spill traffic/dispatch).
__global__ __launch_bounds__(256, 1) void k_attn_mfma(const bf16* __restrict__ q,
    const bf16* __restrict__ k, const bf16* __restrict__ vt,
    bf16* __restrict__ o, int qlen, int orb, int qs) {
  __shared__ bf16 Ps[4][16][520];   // pad 8 keeps ds_read_b128 16B-aligned, 2-way row alias
  int tid = threadIdx.x;
  int wave = tid >> 6, lane = tid & 63;
  int quad = lane >> 4, l16 = lane & 15;
  int b = blockIdx.z, head = blockIdx.y;
  int q0 = blockIdx.x * 64 + wave * 16;

  const bf16* qp = q + (size_t)(b*SEQ + q0 + l16)*qs + head*64 + quad*8;
  bf16x8 aq0 = *(const bf16x8*)(qp);
  bf16x8 aq1 = *(const bf16x8*)(qp + 32);

  f32x4 z = {0.f, 0.f, 0.f, 0.f};
  f32x4 acc[32];
  #pragma unroll
  for (int ni = 0; ni < 32; ni++) acc[ni] = z;
  const bf16* kb = k + (size_t)(b*SEQ + l16)*qs + head*64 + quad*8;
  #pragma unroll
  for (int ni = 0; ni < 32; ni++) {
    const bf16* kp = kb + (size_t)(ni*16)*qs;
    bf16x8 b0 = *(const bf16x8*)(kp);
    bf16x8 b1 = *(const bf16x8*)(kp + 32);
    acc[ni] = __builtin_amdgcn_mfma_f32_16x16x32_bf16(aq0, b0, acc[ni], 0, 0, 0);
    acc[ni] = __builtin_amdgcn_mfma_f32_16x16x32_bf16(aq1, b1, acc[ni], 0, 0, 0);
  }
  float mx[4] = {-3e30f, -3e30f, -3e30f, -3e30f};
  #pragma unroll
  for (int ni = 0; ni < 32; ni++)
    #pragma unroll
    for (int rr = 0; rr < 4; rr++) {
      float s = acc[ni][rr] * 0.125f;
      acc[ni][rr] = s;
      mx[rr] = fmaxf(mx[rr], s);
    }
  #pragma unroll
  for (int off = 1; off <= 8; off <<= 1)
    #pragma unroll
    for (int rr = 0; rr < 4; rr++)
      mx[rr] = fmaxf(mx[rr], __shfl_xor(mx[rr], off));
  float sm[4] = {0.f, 0.f, 0.f, 0.f};
  #pragma unroll
  for (int ni = 0; ni < 32; ni++)
    #pragma unroll
    for (int rr = 0; rr < 4; rr++) {
      float p = __expf(acc[ni][rr] - mx[rr]);
      acc[ni][rr] = p;
      sm[rr] += p;
    }
  #pragma unroll
  for (int off = 1; off <= 8; off <<= 1)
    #pragma unroll
    for (int rr = 0; rr < 4; rr++)
      sm[rr] += __shfl_xor(sm[rr], off);
  #pragma unroll
  for (int ni = 0; ni < 32; ni++)
    #pragma unroll
    for (int rr = 0; rr < 4; rr++)
      Ps[wave][quad*4 + rr][ni*16 + l16] = (bf16)acc[ni][rr];
  const bf16* vtb = vt + ((size_t)(b*NHD + head)*64 + l16)*512 + quad*8;
  f32x4 accO[4] = {z, z, z, z};
  #pragma unroll 4
  for (int kk = 0; kk < 16; kk++) {
    bf16x8 ap = *(const bf16x8*)&Ps[wave][l16][kk*32 + quad*8];
    #pragma unroll
    for (int ni = 0; ni < 4; ni++) {
      bf16x8 bv = *(const bf16x8*)(vtb + (size_t)(ni*16)*512 + kk*32);
      accO[ni] = __builtin_amdgcn_mfma_f32_16x16x32_bf16(ap, bv, accO[ni], 0, 0, 0);
    }
  }
  float inv[4];
  #pragma unroll
  for (int rr = 0; rr < 4; rr++) inv[rr] = 1.f / sm[rr];
  #pragma unroll
  for (int ni = 0; ni < 4; ni++)
    #pragma unroll
    for (int rr = 0; rr < 4; rr++) {
      int row = q0 + quad*4 + rr;
      if (row < qlen)
        o[(size_t)(b*orb + row)*HDIM + head*64 + ni*16 + l16] = (bf16)(accO[ni][rr] * inv[rr]);
    }
}

// ---------------- gather kept rows of h -> hk (zero-pad 240..255), zero ok pad ----------------
__global__ __launch_bounds__(256) void k_gather(const float* __restrict__ h,
                                                float* __restrict__ hk, bf16* __restrict__ ok) {
  int idx = blockIdx.x*256 + threadIdx.x;    // 256*1024 = 262144
  int row = idx >> 10, col = idx & 1023;
  if (row < BATCH*KEEP) {
    int b = row / KEEP, s = row - b*KEEP;
    hk[idx] = h[(size_t)(b*SEQ + s)*HDIM + col];
  } else {
    hk[idx] = 0.f;
    ok[idx] = (bf16)0.f;
  }
}

// ---------------- combined += hk * r[:,e] ----------------
__global__ __launch_bounds__(256) void k_accum(float* __restrict__ comb, const float* __restrict__ hk,
                                               const float* __restrict__ r, int e, int first) {
  int idx = blockIdx.x*256 + threadIdx.x;    // 240*1024 = 245760
  int row = idx >> 10;
  float vv = hk[idx] * r[row*4 + e];
  comb[idx] = (first ? 0.f : comb[idx]) + vv;
}

// ---------------- final proj, split-K x16 with 8-row weight reuse ----------------
__global__ __launch_bounds__(256) void k_proj(const float* __restrict__ comb,
                                              const float* __restrict__ pw,
                                              float* __restrict__ part) {
  int rg = blockIdx.x, ks = blockIdx.y, tid = threadIdx.x;
  __shared__ float xr[8][64];
  for (int i = tid; i < 8*64; i += 256) {
    int r = i >> 6, kk = i & 63;
    xr[r][kk] = comb[(size_t)(rg*8 + r)*HDIM + ks*64 + kk];
  }
  __syncthreads();
  f32x4 acc[8];
  #pragma unroll
  for (int r = 0; r < 8; r++) acc[r] = (f32x4){0.f,0.f,0.f,0.f};
  const float* wp = pw + (size_t)(ks*64)*HDIM + tid*4;
  #pragma unroll 4
  for (int kk = 0; kk < 64; kk++) {
    f32x4 w4 = *(const f32x4*)(wp + (size_t)kk*HDIM);
    #pragma unroll
    for (int r = 0; r < 8; r++) acc[r] += xr[r][kk] * w4;
  }
  #pragma unroll
  for (int r = 0; r < 8; r++)
    *(f32x4*)(part + ((size_t)ks*KEEPT + rg*8 + r)*HDIM + tid*4) = acc[r];
}

__global__ __launch_bounds__(256) void k_ln(const float* __restrict__ part, const float* __restrict__ pb,
    const float* __restrict__ lnw, const float* __restrict__ lnb, float* __restrict__ out) {
  int row = blockIdx.x, tid = threadIdx.x;
  f32x4 acc = *(const f32x4*)(pb + tid*4);
  #pragma unroll
  for (int s = 0; s < 16; s++)
    acc += *(const f32x4*)(part + ((size_t)s*KEEPT + row)*HDIM + tid*4);
  float ps = acc[0]+acc[1]+acc[2]+acc[3];
  #pragma unroll
  for (int off = 32; off; off >>= 1) ps += __shfl_xor(ps, off);
  __shared__ float red1[4], red2[4];
  if ((tid & 63) == 0) red1[tid >> 6] = ps;
  __syncthreads();
  float mu = (red1[0]+red1[1]+red1[2]+red1[3]) * (1.f/HDIM);
  f32x4 d;
  #pragma unroll
  for (int i = 0; i < 4; i++) d[i] = acc[i] - mu;
  float pv = d[0]*d[0]+d[1]*d[1]+d[2]*d[2]+d[3]*d[3];
  #pragma unroll
  for (int off = 32; off; off >>= 1) pv += __shfl_xor(pv, off);
  if ((tid & 63) == 0) red2[tid >> 6] = pv;
  __syncthreads();
  float rs = rsqrtf((red2[0]+red2[1]+red2[2]+red2[3]) * (1.f/HDIM) + EPSV);
  f32x4 lw = *(const f32x4*)(lnw + tid*4);
  f32x4 lb = *(const f32x4*)(lnb + tid*4);
  f32x4 o;
  #pragma unroll
  for (int i = 0; i < 4; i++) o[i] = d[i]*rs*lw[i] + lb[i];
  *(f32x4*)(out + (size_t)row*HDIM + tid*4) = o;
}

extern "C" void kernel_launch(void* const* d_in, const int* in_sizes, int n_in,
                              void* d_out, int out_size, void* d_ws, size_t ws_size,
                              hipStream_t stream) {
  (void)in_sizes; (void)n_in; (void)out_size; (void)ws_size;
  const float* pose = (const float*)d_in[0];
  const float* scene = (const float*)d_in[1];
  const float* rf1w = (const float*)d_in[2];
  const float* rf1b = (const float*)d_in[3];
  const float* rf2w = (const float*)d_in[4];
  const float* rf2b = (const float*)d_in[5];
  const float* anw = (const float*)d_in[6];
  const float* wqw = (const float*)d_in[7];
  const float* wqb = (const float*)d_in[8];
  const float* wkw = (const float*)d_in[9];
  const float* wkb = (const float*)d_in[10];
  const float* wvw = (const float*)d_in[11];
  const float* wvb = (const float*)d_in[12];
  const float* wow = (const float*)d_in[13];
  const float* wob = (const float*)d_in[14];
  const float* fnw = (const float*)d_in[15];
  const float* w1w = (const float*)d_in[16];
  const float* w2w = (const float*)d_in[17];
  const float* w3w = (const float*)d_in[18];
  const float* pw  = (const float*)d_in[19];
  const float* pb  = (const float*)d_in[20];
  const float* lnw = (const float*)d_in[21];
  const float* lnb = (const float*)d_in[22];
  float* out = (float*)d_out;

  char* p = (char*)d_ws;
  auto carve = [&](size_t bytes) { void* r = (void*)p; p += (bytes + 255) & ~(size_t)255; return r; };
  // Footprint parity with the round-2 passing kernel: w13T (11.5 MB) replaces w1T+w3T;
  // part aliases a1 (dead outside the expert loop at l=0 now that w13 writes g directly).
  float* x   = (float*)carve((size_t)TOK*HDIM*4);
  float* h   = (float*)carve((size_t)TOK*HDIM*4);
  bf16* xn   = (bf16*)carve((size_t)TOK*HDIM*2);
  bf16* qkv3 = (bf16*)carve((size_t)TOK*3072*2);     // fused Q|K|V, row stride 3072
  bf16* ob_  = (bf16*)carve((size_t)TOK*HDIM*2);
  bf16* vt   = (bf16*)carve((size_t)TOK*HDIM*2);     // vt[b][h][64][512]
  bf16* a1   = (bf16*)carve((size_t)TOK*HFF*2);      // reserved (part alias)
  bf16* g    = (bf16*)carve((size_t)TOK*HFF*2);
  bf16* qkvT = (bf16*)carve((size_t)3072*HDIM*2);    // stacked wq^T|wk^T|wv^T [3072][1024]
  bf16* woT  = (bf16*)carve((size_t)HDIM*HDIM*2);
  bf16* w13T = (bf16*)carve((size_t)2*HDIM*HFF*2);   // interleaved w1^T|w3^T [5632][1024]
  bf16* w2T  = (bf16*)carve((size_t)HFF*HDIM*2);
  float* hk  = (float*)carve((size_t)MKP*HDIM*4);
  bf16* hnk  = (bf16*)carve((size_t)MKP*HDIM*2);
  bf16* okb  = (bf16*)carve((size_t)MKP*HDIM*2);
  float* comb = (float*)carve((size_t)KEEPT*HDIM*4);
  float* rbuf = (float*)carve((size_t)KEEPT*4*4);
  float* qkvb = (float*)carve((size_t)8*3072*4);     // packed per-(e,l) qkv biases
  float* part = (float*)a1;                          // alias: 16*KEEPT*HDIM*4 = 15.7 MB <= 23 MB

  k_concat<<<4096, 256, 0, stream>>>(pose, scene, x);
  k_router<<<KEEPT, 64, 0, stream>>>(x, rf1w, rf1b, rf2w, rf2b, rbuf);
  k_pack_bias<<<96, 256, 0, stream>>>(wqb, wkb, wvb, qkvb);

  for (int e = 0; e < NE; e++) {
    for (int l = 0; l < NL; l++) {
      int el = e*NL + l;
      ConvArgs ca;
      ca.src[0] = wqw + (size_t)el*HDIM*HDIM;
      ca.src[1] = wkw + (size_t)el*HDIM*HDIM;
      ca.src[2] = wvw + (size_t)el*HDIM*HDIM;
      ca.src[3] = wow + (size_t)el*HDIM*HDIM;
      ca.src[4] = w1w + (size_t)el*HDIM*HFF;
      ca.src[5] = w3w + (size_t)el*HDIM*HFF;
      ca.src[6] = w2w + (size_t)el*HFF*HDIM;
      ca.dst[0] = qkvT;
      ca.dst[1] = qkvT + (size_t)1024*HDIM;
      ca.dst[2] = qkvT + (size_t)2048*HDIM;
      ca.dst[3] = woT;
      ca.dst[4] = w13T; ca.dst[5] = w13T; ca.dst[6] = w2T;
      k_convertT<<<12544, 256, 0, stream>>>(ca);

      const float* src_h = (l == 0) ? x : h;
      k_rmsnorm<<<TOK, 256, 0, stream>>>(src_h, anw + (size_t)el*HDIM, xn);
      // fused QKV GEMM: [4096,1024] @ [3072,1024]^T -> [4096,3072]
      k_gemm256<<<dim3(12, 16), 512, 0, stream>>>(xn, qkvT, qkvb + (size_t)el*3072, qkv3, 3072, HDIM, 0);
      k_vtrans<<<dim3(8, NHD, BATCH), 256, 0, stream>>>(qkv3 + 2048, vt, 3072);

      if (l == 0) {
        k_attn_mfma<<<dim3(8, NHD, BATCH), 256, 0, stream>>>(qkv3, qkv3 + 1024, vt, ob_, SEQ, SEQ, 3072);
        k_gemm<<<dim3(8, 32), 256, 0, stream>>>(ob_, woT, wob + (size_t)el*HDIM, x, nullptr, h, nullptr, HDIM, HDIM);
        k_rmsnorm<<<TOK, 256, 0, stream>>>(h, fnw + (size_t)el*HDIM, xn);
        // fused w1|w3 + SwiGLU: [4096,1024] @ [5632,1024]^T -> g [4096,2816]
        k_gemm256<<<dim3(22, 16), 512, 0, stream>>>(xn, w13T, nullptr, g, 2*HFF, HDIM, 1);
        k_gemm<<<dim3(8, 32), 256, 0, stream>>>(g, w2T, nullptr, h, nullptr, h, nullptr, HDIM, HFF);
      } else {
        k_attn_mfma<<<dim3(1, NHD, BATCH), 256, 0, stream>>>(qkv3, qkv3 + 1024, vt, okb, KEEP, KEEP, 3072);
        k_gather<<<1024, 256, 0, stream>>>(h, hk, okb);
        k_gemm<<<dim3(8, 2), 256, 0, stream>>>(okb, woT, wob + (size_t)el*HDIM, hk, nullptr, hk, nullptr, HDIM, HDIM);
        k_rmsnorm<<<MKP, 256, 0, stream>>>(hk, fnw + (size_t)el*HDIM, hnk);
        k_gemm256<<<dim3(22, 1), 512, 0, stream>>>(hnk, w13T, nullptr, g, 2*HFF, HDIM, 1);
        k_gemm<<<dim3(8, 2), 256, 0, stream>>>(g, w2T, nullptr, hk, nullptr, hk, nullptr, HDIM, HFF);
        k_accum<<<960, 256, 0, stream>>>(comb, hk, rbuf, e, (e == 0) ? 1 : 0);
      }
    }
  }
  k_proj<<<dim3(30, 16), 256, 0, stream>>>(comb, pw, part);
  k_ln<<<KEEPT, 256, 0, stream>>>(part, pb, lnw, lnb, out);
}

// Round 4
// 2833.873 us; speedup vs baseline: 1.3754x; 1.0135x over previous
//
#include <hip/hip_runtime.h>
#include <cstdint>
#include <cstddef>

#define HDIM 1024
#define NE 4
#define NL 2
#define NHD 16
#define SEQ 512
#define BATCH 8
#define HFF 2816
#define KEEP 30
#define KEEPT (BATCH*KEEP)  // 240
#define TOK (BATCH*SEQ)   // 4096
#define MKP 256           // padded keep-rows (240 -> 256)
#define EPSV 1e-5f

typedef __bf16 bf16;
typedef bf16 bf16x8 __attribute__((ext_vector_type(8)));
typedef bf16 bf16x4 __attribute__((ext_vector_type(4)));
typedef float f32x4 __attribute__((ext_vector_type(4)));

__device__ __forceinline__ void gll16(const bf16* g, bf16* l) {
  __builtin_amdgcn_global_load_lds((const __attribute__((address_space(1))) void*)g,
                                   (__attribute__((address_space(3))) void*)l, 16, 0, 0);
}

// ---------------- concat pose|scene -> x [TOK, HDIM] ----------------
__global__ __launch_bounds__(256) void k_concat(const float* __restrict__ pose,
                                                const float* __restrict__ scene,
                                                float* __restrict__ x) {
  int idx4 = blockIdx.x * 256 + threadIdx.x;     // over TOK*HDIM/4 = 1048576
  int tok = idx4 >> 8;                           // HDIM/4 = 256 vec4 per token
  int c = (idx4 & 255) << 2;
  int b = tok >> 9, s = tok & 511;
  const float* src = (s < 256) ? (pose + ((size_t)(b*256 + s)*HDIM + c))
                               : (scene + ((size_t)(b*256 + (s-256))*HDIM + c));
  *(f32x4*)(x + (size_t)tok*HDIM + c) = *(const f32x4*)src;
}

// ---------------- router (only the 240 kept tokens) ----------------
__global__ __launch_bounds__(64) void k_router(const float* __restrict__ x,
                                               const float* __restrict__ w1, const float* __restrict__ b1,
                                               const float* __restrict__ w2, const float* __restrict__ b2,
                                               float* __restrict__ r) {
  int row = blockIdx.x;                 // b*KEEP + s
  int b = row / KEEP, s = row - b*KEEP;
  int lane = threadIdx.x;
  const float* xr = x + (size_t)(b*SEQ + s)*HDIM;
  float p0=0.f, p1=0.f, p2=0.f, p3=0.f;
  for (int k2 = lane; k2 < HDIM; k2 += 64) {
    float xv = xr[k2];
    const float* wr = w1 + k2*4;
    p0 += xv*wr[0]; p1 += xv*wr[1]; p2 += xv*wr[2]; p3 += xv*wr[3];
  }
  #pragma unroll
  for (int off = 32; off; off >>= 1) {
    p0 += __shfl_xor(p0, off); p1 += __shfl_xor(p1, off);
    p2 += __shfl_xor(p2, off); p3 += __shfl_xor(p3, off);
  }
  if (lane == 0) {
    float gg[4] = {p0 + b1[0], p1 + b1[1], p2 + b1[2], p3 + b1[3]};
    #pragma unroll
    for (int i = 0; i < 4; i++) gg[i] = 0.5f*gg[i]*(1.f + erff(gg[i]*0.70710678f));
    float rr[4], sum = 0.f;
    #pragma unroll
    for (int i = 0; i < 4; i++) {
      float a = b2[i];
      #pragma unroll
      for (int j = 0; j < 4; j++) a += gg[j]*w2[j*4 + i];
      rr[i] = 1.f/(1.f + __expf(-a));
      sum += rr[i];
    }
    float inv = 1.f / fmaxf(sum, 1e-8f);
    #pragma unroll
    for (int i = 0; i < 4; i++) r[row*4 + i] = rr[i]*inv;
  }
}

// ---------------- RMSNorm: fp32 in -> bf16 out ----------------
__global__ __launch_bounds__(256) void k_rmsnorm(const float* __restrict__ in,
                                                 const float* __restrict__ w,
                                                 bf16* __restrict__ out) {
  int row = blockIdx.x, tid = threadIdx.x;
  const float* xr = in + (size_t)row*HDIM;
  f32x4 v = *(const f32x4*)(xr + tid*4);
  float ss = v[0]*v[0] + v[1]*v[1] + v[2]*v[2] + v[3]*v[3];
  #pragma unroll
  for (int off = 32; off; off >>= 1) ss += __shfl_xor(ss, off);
  __shared__ float part[4];
  if ((tid & 63) == 0) part[tid >> 6] = ss;
  __syncthreads();
  float scale = rsqrtf((part[0]+part[1]+part[2]+part[3]) * (1.f/HDIM) + EPSV);
  f32x4 wv = *(const f32x4*)(w + tid*4);
  bf16x4 o;
  #pragma unroll
  for (int i = 0; i < 4; i++) o[i] = (bf16)(v[i]*scale*wv[i]);
  *(bf16x4*)(out + (size_t)row*HDIM + tid*4) = o;
}

// ------------- per-(e,l) weight convert: fp32 [K,N] -> bf16 [N,K] -------------
// t=4 (w1) / t=5 (w3) write into ONE stacked buffer with 16-column interleave:
// dest row for source col gr:  (gr>>4)*32 + (t==5 ? 16 : 0) + (gr&15)
// so the fused w13 GEMM's wave holds matching silu pairs in adjacent ni slots.
struct ConvArgs { const float* src[7]; bf16* dst[7]; };
__global__ __launch_bounds__(256) void k_convertT(ConvArgs a) {
  int id = blockIdx.x;   // 12544 tiles total
  int t, base;
  if (id < 4096)      { t = id >> 10; base = t << 10; }
  else if (id < 6912) { t = 4; base = 4096; }
  else if (id < 9728) { t = 5; base = 6912; }
  else                { t = 6; base = 9728; }
  int K = (t == 6) ? HFF : HDIM;
  int N = (t == 4 || t == 5) ? HFF : HDIM;
  int tl = id - base;
  int tilesN = N >> 5;
  int tk = tl / tilesN, tn = tl - tk*tilesN;
  __shared__ float tile[32][33];
  int tx = threadIdx.x & 31, ty = threadIdx.x >> 5;
  const float* src = a.src[t];
  bf16* dst = a.dst[t];
  #pragma unroll
  for (int i = 0; i < 4; i++) {
    int rr = ty + i*8;
    tile[rr][tx] = src[(size_t)(tk*32 + rr)*N + tn*32 + tx];
  }
  __syncthreads();
  #pragma unroll
  for (int i = 0; i < 4; i++) {
    int rr = ty + i*8;
    int gr = tn*32 + rr;
    size_t dr;
    if (t == 4)      dr = (size_t)((gr >> 4)*32 + (gr & 15));
    else if (t == 5) dr = (size_t)((gr >> 4)*32 + 16 + (gr & 15));
    else             dr = (size_t)gr;
    dst[dr*K + tk*32 + tx] = (bf16)tile[tx][rr];
  }
}

// ---------------- bias pack: qkvb[el][0:1024|1024:2048|2048:3072] = wqb|wkb|wvb ----------------
__global__ __launch_bounds__(256) void k_pack_bias(const float* __restrict__ qb, const float* __restrict__ kb,
                                                   const float* __restrict__ vb, float* __restrict__ dst) {
  int idx = blockIdx.x*256 + threadIdx.x;  // 8*3072 = 24576
  int el = idx / 3072, j = idx - el*3072;
  float v = (j < 1024) ? qb[el*1024 + j]
          : (j < 2048) ? kb[el*1024 + j - 1024]
                       : vb[el*1024 + j - 2048];
  dst[idx] = v;
}

// ===== LDS bank-swizzle (both GEMMs) ========================================
// Linear [rows][32]bf16 LDS (row = 64 B) makes quad-reads hit 2 bank-groups
// (8-way conflict; measured 4.3M cycles/dispatch). Involution: granule(16B
// chunks, 0..3) ^= (row>>1)&3. gll writes linearly, so the SOURCE granule is
// pre-swizzled per-lane and the READ applies the same XOR (rule #21):
//   stage: srcg = (lane&3) ^ ((lane>>3)&3)   [row bases are multiples of 16]
//   read : swg  = quad ^ ((l16>>1)&3)        [wm/wn/i*16 drop out of (row>>1)&3]
// Bank-starts become (row&1)*16 + swg*4 -> all 8 groups, 2 lanes each (free).
// ============================================================================

// ---------------- 128x128 bf16 MFMA GEMM (2-barrier, gll staging) ----------------
// kept for wo / w2 / small l=1 GEMMs (grids where 256^2 would under-fill CUs)
__global__ __launch_bounds__(256) void k_gemm(const bf16* __restrict__ A, const bf16* __restrict__ Bt,
    const float* __restrict__ bias, const float* __restrict__ resid, const bf16* __restrict__ siluSrc,
    float* __restrict__ outF, bf16* __restrict__ outB, int N, int K) {
  __shared__ bf16 As[128*32];
  __shared__ bf16 Bs[128*32];
  int tid = threadIdx.x;
  int wave = tid >> 6, lane = tid & 63;
  int quad = lane >> 4, l16 = lane & 15;
  int wm = (wave >> 1) * 64, wn = (wave & 1) * 64;
  int m0 = blockIdx.y * 128, n0 = blockIdx.x * 128;
  f32x4 zero4 = {0.f, 0.f, 0.f, 0.f};
  f32x4 acc[4][4];
  #pragma unroll
  for (int i = 0; i < 4; i++)
    #pragma unroll
    for (int j = 0; j < 4; j++) acc[i][j] = zero4;
  int srow = wave*32 + (lane >> 2);
  int sg = (lane & 3) ^ ((lane >> 3) & 3);      // pre-swizzled source granule
  int swg = quad ^ ((l16 >> 1) & 3);            // swizzled read granule
  const bf16* Ap = A + (size_t)(m0 + srow)*K + sg*8;
  const bf16* Bp = Bt + (size_t)(n0 + srow)*K + sg*8;
  bf16* AsW = As + wave*1024;   // wave-uniform LDS base (elements)
  bf16* BsW = Bs + wave*1024;
  for (int k0 = 0; k0 < K; k0 += 32) {
    __syncthreads();
    gll16(Ap + k0,                AsW);
    gll16(Ap + k0 + (size_t)16*K, AsW + 512);
    gll16(Bp + k0,                BsW);
    gll16(Bp + k0 + (size_t)16*K, BsW + 512);
    __syncthreads();
    bf16x8 af[4], bq[4];
    #pragma unroll
    for (int i = 0; i < 4; i++) af[i] = *(const bf16x8*)&As[(wm + i*16 + l16)*32 + swg*8];
    #pragma unroll
    for (int i = 0; i < 4; i++) bq[i] = *(const bf16x8*)&Bs[(wn + i*16 + l16)*32 + swg*8];
    #pragma unroll
    for (int mi = 0; mi < 4; mi++)
      #pragma unroll
      for (int ni = 0; ni < 4; ni++)
        acc[mi][ni] = __builtin_amdgcn_mfma_f32_16x16x32_bf16(af[mi], bq[ni], acc[mi][ni], 0, 0, 0);
  }
  #pragma unroll
  for (int mi = 0; mi < 4; mi++) {
    #pragma unroll
    for (int ni = 0; ni < 4; ni++) {
      int colg = n0 + wn + ni*16 + l16;
      float bv = bias ? bias[colg] : 0.f;
      #pragma unroll
      for (int rr = 0; rr < 4; rr++) {
        int rowg = m0 + wm + mi*16 + quad*4 + rr;
        size_t off = (size_t)rowg*N + colg;
        float vv = acc[mi][ni][rr] + bv;
        if (resid) vv += resid[off];
        if (siluSrc) { float a = (float)siluSrc[off]; vv *= a / (1.f + __expf(-a)); }
        if (outF) outF[off] = vv;
        else      outB[off] = (bf16)vv;
      }
    }
  }
}

// ---------------- 256x256 counted-vmcnt phase GEMM (T3+T4+T5, plain HIP) ----------------
// 512 thr = 8 waves (2M x 4N), per-wave C = 128x64 (acc[8][4]); BK=32, LDS dbuf 64 KB.
// Staged 2 K-tiles ahead via global_load_lds; vmcnt(4) counted waits (never 0 in loop);
// raw s_barrier via asm (NO __syncthreads -> no vmcnt(0) drain). Buffer for kt+2 is
// written only after phase-1's post-MFMA barrier. swiglu=1: Bt is 16-col-interleaved
// w1|w3, epilogue writes g = silu(a1)*a3 with stride N/2 (no intermediate buffer).
__global__ __launch_bounds__(512, 2) void k_gemm256(const bf16* __restrict__ A, const bf16* __restrict__ Bt,
    const float* __restrict__ bias, bf16* __restrict__ out, int N, int K, int swiglu) {
  __shared__ __align__(16) bf16 As[2][256*32];
  __shared__ __align__(16) bf16 Bs[2][256*32];
  int tid = threadIdx.x;
  int wave = tid >> 6, lane = tid & 63;
  int quad = lane >> 4, l16 = lane & 15;
  int wm128 = (wave >> 2) * 128;       // 2 waves in M
  int wn64  = (wave & 3) * 64;         // 4 waves in N
  int m0 = blockIdx.y * 256, n0 = blockIdx.x * 256;
  int NT = K >> 5;
  f32x4 z = {0.f, 0.f, 0.f, 0.f};
  f32x4 acc[8][4];
  #pragma unroll
  for (int i = 0; i < 8; i++)
    #pragma unroll
    for (int j = 0; j < 4; j++) acc[i][j] = z;
  int sg = (lane & 3) ^ ((lane >> 3) & 3);      // pre-swizzled source granule
  int swg = quad ^ ((l16 >> 1) & 3);            // swizzled read granule
  const bf16* aSrc = A + (size_t)(m0 + wave*16 + (lane>>2))*K + sg*8;
  const bf16* bSrc = Bt + (size_t)(n0 + wave*16 + (lane>>2))*K + sg*8;
  auto stage = [&](int buf, int kt) {
    #pragma unroll
    for (int r = 0; r < 2; r++) {
      gll16(aSrc + (size_t)(r*128)*K + kt*32, &As[buf][(r*128 + wave*16)*32]);
      gll16(bSrc + (size_t)(r*128)*K + kt*32, &Bs[buf][(r*128 + wave*16)*32]);
    }
  };
  stage(0, 0);
  stage(1, 1);
  asm volatile("s_waitcnt vmcnt(4)" ::: "memory");   // tile 0 landed (mine); barrier -> all
  asm volatile("s_barrier" ::: "memory");
  for (int kt = 0; kt < NT; ++kt) {
    int cur = kt & 1;
    bf16x8 pb[4];
    // ---- phase 0: C rows wm128+0..63 ----
    {
      bf16x8 pa[4];
      #pragma unroll
      for (int i = 0; i < 4; i++)
        pa[i] = *(const bf16x8*)&As[cur][(wm128 + i*16 + l16)*32 + swg*8];
      #pragma unroll
      for (int i = 0; i < 4; i++)
        pb[i] = *(const bf16x8*)&Bs[cur][(wn64 + i*16 + l16)*32 + swg*8];
      asm volatile("s_barrier" ::: "memory");
      __builtin_amdgcn_s_setprio(1);
      #pragma unroll
      for (int mi = 0; mi < 4; mi++)
        #pragma unroll
        for (int ni = 0; ni < 4; ni++)
          acc[mi][ni] = __builtin_amdgcn_mfma_f32_16x16x32_bf16(pa[mi], pb[ni], acc[mi][ni], 0, 0, 0);
      __builtin_amdgcn_s_setprio(0);
      asm volatile("s_barrier" ::: "memory");
    }
    // ---- phase 1: C rows wm128+64..127 ----
    {
      bf16x8 pa[4];
      #pragma unroll
      for (int i = 0; i < 4; i++)
        pa[i] = *(const bf16x8*)&As[cur][(wm128 + 64 + i*16 + l16)*32 + swg*8];
      asm volatile("s_barrier" ::: "memory");
      __builtin_amdgcn_s_setprio(1);
      #pragma unroll
      for (int mi = 0; mi < 4; mi++)
        #pragma unroll
        for (int ni = 0; ni < 4; ni++)
          acc[4+mi][ni] = __builtin_amdgcn_mfma_f32_16x16x32_bf16(pa[mi], pb[ni], acc[4+mi][ni], 0, 0, 0);
      __builtin_amdgcn_s_setprio(0);
      asm volatile("s_barrier" ::: "memory");   // all waves done reading buf[cur]
    }
    if (kt + 1 < NT) {
      if (kt + 2 < NT) {
        stage(cur, kt + 2);                     // overwrite freed buffer; lands over next iter
        asm volatile("s_waitcnt vmcnt(4)" ::: "memory");  // tile kt+1 complete, kt+2 in flight
      } else {
        asm volatile("s_waitcnt vmcnt(0)" ::: "memory");  // last tile (issued long ago)
      }
      asm volatile("s_barrier" ::: "memory");
    }
  }
  // ---- epilogue (proven C layout: row = quad*4+rr, col = l16) ----
  if (!swiglu) {
    #pragma unroll
    for (int ni = 0; ni < 4; ni++) {
      int colg = n0 + wn64 + ni*16 + l16;
      float bv = bias ? bias[colg] : 0.f;
      #pragma unroll
      for (int mi = 0; mi < 8; mi++)
        #pragma unroll
        for (int rr = 0; rr < 4; rr++) {
          int rowg = m0 + wm128 + mi*16 + quad*4 + rr;
          out[(size_t)rowg*N + colg] = (bf16)(acc[mi][ni][rr] + bv);
        }
    }
  } else {
    int half = N >> 1;
    #pragma unroll
    for (int np = 0; np < 2; np++) {
      int colo = ((n0 + wn64) >> 1) + np*16 + l16;
      #pragma unroll
      for (int mi = 0; mi < 8; mi++)
        #pragma unroll
        for (int rr = 0; rr < 4; rr++) {
          int rowg = m0 + wm128 + mi*16 + quad*4 + rr;
          float xv = acc[mi][np*2][rr];
          float yv = acc[mi][np*2+1][rr];
          out[(size_t)rowg*half + colo] = (bf16)(xv / (1.f + __expf(-xv)) * yv);
        }
    }
  }
}

// ---------------- V transpose: vt[b][h][d][s] = v[(b*SEQ+s)*vs + h*64+d] ----------------
__global__ __launch_bounds__(256) void k_vtrans(const bf16* __restrict__ v, bf16* __restrict__ vt, int vs) {
  __shared__ bf16 t[64][72];
  int b = blockIdx.z, h = blockIdx.y, s0 = blockIdx.x * 64;
  int r = threadIdx.x >> 2, c0 = (threadIdx.x & 3) * 16;
  const bf16* vp = v + (size_t)(b*SEQ + s0 + r)*vs + h*64 + c0;
  bf16x8 v0 = *(const bf16x8*)vp;
  bf16x8 v1 = *(const bf16x8*)(vp + 8);
  #pragma unroll
  for (int j = 0; j < 8; j++) { t[r][c0+j] = v0[j]; t[r][c0+8+j] = v1[j]; }
  __syncthreads();
  bf16x8 o0, o1;
  #pragma unroll
  for (int j = 0; j < 8; j++) { o0[j] = t[c0+j][r]; o1[j] = t[c0+8+j][r]; }
  bf16* op = vt + ((size_t)(b*NHD + h)*64 + r)*512 + s0 + c0;
  *(bf16x8*)op = o0;
  *(bf16x8*)(op + 8) = o1;
}

// ---------------- MFMA attention ----------------
// ALL loops touching acc[32] are FULLY unrolled — partial unroll demotes the
// 128-VGPR accumulator array to scratch (R1: 765 MB HBM spill traffic/dispatch).
__global__ __launch_bounds__(256, 1) void k_attn_mfma(const bf16* __restrict__ q,
    const bf16* __restrict__ k, const bf16* __restrict__ vt,
    bf16* __restrict__ o, int qlen, int orb, int qs) {
  __shared__ bf16 Ps[4][16][520];   // pad 8 keeps ds_read_b128 16B-aligned, 2-way row alias
  int tid = threadIdx.x;
  int wave = tid >> 6, lane = tid & 63;
  int quad = lane >> 4, l16 = lane & 15;
  int b = blockIdx.z, head = blockIdx.y;
  int q0 = blockIdx.x * 64 + wave * 16;

  const bf16* qp = q + (size_t)(b*SEQ + q0 + l16)*qs + head*64 + quad*8;
  bf16x8 aq0 = *(const bf16x8*)(qp);
  bf16x8 aq1 = *(const bf16x8*)(qp + 32);

  f32x4 z = {0.f, 0.f, 0.f, 0.f};
  f32x4 acc[32];
  #pragma unroll
  for (int ni = 0; ni < 32; ni++) acc[ni] = z;
  const bf16* kb = k + (size_t)(b*SEQ + l16)*qs + head*64 + quad*8;
  #pragma unroll
  for (int ni = 0; ni < 32; ni++) {
    const bf16* kp = kb + (size_t)(ni*16)*qs;
    bf16x8 b0 = *(const bf16x8*)(kp);
    bf16x8 b1 = *(const bf16x8*)(kp + 32);
    acc[ni] = __builtin_amdgcn_mfma_f32_16x16x32_bf16(aq0, b0, acc[ni], 0, 0, 0);
    acc[ni] = __builtin_amdgcn_mfma_f32_16x16x32_bf16(aq1, b1, acc[ni], 0, 0, 0);
  }
  float mx[4] = {-3e30f, -3e30f, -3e30f, -3e30f};
  #pragma unroll
  for (int ni = 0; ni < 32; ni++)
    #pragma unroll
    for (int rr = 0; rr < 4; rr++) {
      float s = acc[ni][rr] * 0.125f;
      acc[ni][rr] = s;
      mx[rr] = fmaxf(mx[rr], s);
    }
  #pragma unroll
  for (int off = 1; off <= 8; off <<= 1)
    #pragma unroll
    for (int rr = 0; rr < 4; rr++)
      mx[rr] = fmaxf(mx[rr], __shfl_xor(mx[rr], off));
  float sm[4] = {0.f, 0.f, 0.f, 0.f};
  #pragma unroll
  for (int ni = 0; ni < 32; ni++)
    #pragma unroll
    for (int rr = 0; rr < 4; rr++) {
      float p = __expf(acc[ni][rr] - mx[rr]);
      acc[ni][rr] = p;
      sm[rr] += p;
    }
  #pragma unroll
  for (int off = 1; off <= 8; off <<= 1)
    #pragma unroll
    for (int rr = 0; rr < 4; rr++)
      sm[rr] += __shfl_xor(sm[rr], off);
  #pragma unroll
  for (int ni = 0; ni < 32; ni++)
    #pragma unroll
    for (int rr = 0; rr < 4; rr++)
      Ps[wave][quad*4 + rr][ni*16 + l16] = (bf16)acc[ni][rr];
  const bf16* vtb = vt + ((size_t)(b*NHD + head)*64 + l16)*512 + quad*8;
  f32x4 accO[4] = {z, z, z, z};
  #pragma unroll 4
  for (int kk = 0; kk < 16; kk++) {
    bf16x8 ap = *(const bf16x8*)&Ps[wave][l16][kk*32 + quad*8];
    #pragma unroll
    for (int ni = 0; ni < 4; ni++) {
      bf16x8 bv = *(const bf16x8*)(vtb + (size_t)(ni*16)*512 + kk*32);
      accO[ni] = __builtin_amdgcn_mfma_f32_16x16x32_bf16(ap, bv, accO[ni], 0, 0, 0);
    }
  }
  float inv[4];
  #pragma unroll
  for (int rr = 0; rr < 4; rr++) inv[rr] = 1.f / sm[rr];
  #pragma unroll
  for (int ni = 0; ni < 4; ni++)
    #pragma unroll
    for (int rr = 0; rr < 4; rr++) {
      int row = q0 + quad*4 + rr;
      if (row < qlen)
        o[(size_t)(b*orb + row)*HDIM + head*64 + ni*16 + l16] = (bf16)(accO[ni][rr] * inv[rr]);
    }
}

// ---------------- gather kept rows of h -> hk (zero-pad 240..255), zero ok pad ----------------
__global__ __launch_bounds__(256) void k_gather(const float* __restrict__ h,
                                                float* __restrict__ hk, bf16* __restrict__ ok) {
  int idx = blockIdx.x*256 + threadIdx.x;    // 256*1024 = 262144
  int row = idx >> 10, col = idx & 1023;
  if (row < BATCH*KEEP) {
    int b = row / KEEP, s = row - b*KEEP;
    hk[idx] = h[(size_t)(b*SEQ + s)*HDIM + col];
  } else {
    hk[idx] = 0.f;
    ok[idx] = (bf16)0.f;
  }
}

// ---------------- combined += hk * r[:,e] ----------------
__global__ __launch_bounds__(256) void k_accum(float* __restrict__ comb, const float* __restrict__ hk,
                                               const float* __restrict__ r, int e, int first) {
  int idx = blockIdx.x*256 + threadIdx.x;    // 240*1024 = 245760
  int row = idx >> 10;
  float vv = hk[idx] * r[row*4 + e];
  comb[idx] = (first ? 0.f : comb[idx]) + vv;
}

// ---------------- final proj, split-K x16 with 8-row weight reuse ----------------
__global__ __launch_bounds__(256) void k_proj(const float* __restrict__ comb,
                                              const float* __restrict__ pw,
                                              float* __restrict__ part) {
  int rg = blockIdx.x, ks = blockIdx.y, tid = threadIdx.x;
  __shared__ float xr[8][64];
  for (int i = tid; i < 8*64; i += 256) {
    int r = i >> 6, kk = i & 63;
    xr[r][kk] = comb[(size_t)(rg*8 + r)*HDIM + ks*64 + kk];
  }
  __syncthreads();
  f32x4 acc[8];
  #pragma unroll
  for (int r = 0; r < 8; r++) acc[r] = (f32x4){0.f,0.f,0.f,0.f};
  const float* wp = pw + (size_t)(ks*64)*HDIM + tid*4;
  #pragma unroll 4
  for (int kk = 0; kk < 64; kk++) {
    f32x4 w4 = *(const f32x4*)(wp + (size_t)kk*HDIM);
    #pragma unroll
    for (int r = 0; r < 8; r++) acc[r] += xr[r][kk] * w4;
  }
  #pragma unroll
  for (int r = 0; r < 8; r++)
    *(f32x4*)(part + ((size_t)ks*KEEPT + rg*8 + r)*HDIM + tid*4) = acc[r];
}

__global__ __launch_bounds__(256) void k_ln(const float* __restrict__ part, const float* __restrict__ pb,
    const float* __restrict__ lnw, const float* __restrict__ lnb, float* __restrict__ out) {
  int row = blockIdx.x, tid = threadIdx.x;
  f32x4 acc = *(const f32x4*)(pb + tid*4);
  #pragma unroll
  for (int s = 0; s < 16; s++)
    acc += *(const f32x4*)(part + ((size_t)s*KEEPT + row)*HDIM + tid*4);
  float ps = acc[0]+acc[1]+acc[2]+acc[3];
  #pragma unroll
  for (int off = 32; off; off >>= 1) ps += __shfl_xor(ps, off);
  __shared__ float red1[4], red2[4];
  if ((tid & 63) == 0) red1[tid >> 6] = ps;
  __syncthreads();
  float mu = (red1[0]+red1[1]+red1[2]+red1[3]) * (1.f/HDIM);
  f32x4 d;
  #pragma unroll
  for (int i = 0; i < 4; i++) d[i] = acc[i] - mu;
  float pv = d[0]*d[0]+d[1]*d[1]+d[2]*d[2]+d[3]*d[3];
  #pragma unroll
  for (int off = 32; off; off >>= 1) pv += __shfl_xor(pv, off);
  if ((tid & 63) == 0) red2[tid >> 6] = pv;
  __syncthreads();
  float rs = rsqrtf((red2[0]+red2[1]+red2[2]+red2[3]) * (1.f/HDIM) + EPSV);
  f32x4 lw = *(const f32x4*)(lnw + tid*4);
  f32x4 lb = *(const f32x4*)(lnb + tid*4);
  f32x4 o;
  #pragma unroll
  for (int i = 0; i < 4; i++) o[i] = d[i]*rs*lw[i] + lb[i];
  *(f32x4*)(out + (size_t)row*HDIM + tid*4) = o;
}

extern "C" void kernel_launch(void* const* d_in, const int* in_sizes, int n_in,
                              void* d_out, int out_size, void* d_ws, size_t ws_size,
                              hipStream_t stream) {
  (void)in_sizes; (void)n_in; (void)out_size; (void)ws_size;
  const float* pose = (const float*)d_in[0];
  const float* scene = (const float*)d_in[1];
  const float* rf1w = (const float*)d_in[2];
  const float* rf1b = (const float*)d_in[3];
  const float* rf2w = (const float*)d_in[4];
  const float* rf2b = (const float*)d_in[5];
  const float* anw = (const float*)d_in[6];
  const float* wqw = (const float*)d_in[7];
  const float* wqb = (const float*)d_in[8];
  const float* wkw = (const float*)d_in[9];
  const float* wkb = (const float*)d_in[10];
  const float* wvw = (const float*)d_in[11];
  const float* wvb = (const float*)d_in[12];
  const float* wow = (const float*)d_in[13];
  const float* wob = (const float*)d_in[14];
  const float* fnw = (const float*)d_in[15];
  const float* w1w = (const float*)d_in[16];
  const float* w2w = (const float*)d_in[17];
  const float* w3w = (const float*)d_in[18];
  const float* pw  = (const float*)d_in[19];
  const float* pb  = (const float*)d_in[20];
  const float* lnw = (const float*)d_in[21];
  const float* lnb = (const float*)d_in[22];
  float* out = (float*)d_out;

  char* p = (char*)d_ws;
  auto carve = [&](size_t bytes) { void* r = (void*)p; p += (bytes + 255) & ~(size_t)255; return r; };
  // Footprint parity with the round-2 passing kernel: w13T (11.5 MB) replaces w1T+w3T;
  // part aliases a1 (dead outside the expert loop at l=0 now that w13 writes g directly).
  float* x   = (float*)carve((size_t)TOK*HDIM*4);
  float* h   = (float*)carve((size_t)TOK*HDIM*4);
  bf16* xn   = (bf16*)carve((size_t)TOK*HDIM*2);
  bf16* qkv3 = (bf16*)carve((size_t)TOK*3072*2);     // fused Q|K|V, row stride 3072
  bf16* ob_  = (bf16*)carve((size_t)TOK*HDIM*2);
  bf16* vt   = (bf16*)carve((size_t)TOK*HDIM*2);     // vt[b][h][64][512]
  bf16* a1   = (bf16*)carve((size_t)TOK*HFF*2);      // reserved (part alias)
  bf16* g    = (bf16*)carve((size_t)TOK*HFF*2);
  bf16* qkvT = (bf16*)carve((size_t)3072*HDIM*2);    // stacked wq^T|wk^T|wv^T [3072][1024]
  bf16* woT  = (bf16*)carve((size_t)HDIM*HDIM*2);
  bf16* w13T = (bf16*)carve((size_t)2*HDIM*HFF*2);   // interleaved w1^T|w3^T [5632][1024]
  bf16* w2T  = (bf16*)carve((size_t)HFF*HDIM*2);
  float* hk  = (float*)carve((size_t)MKP*HDIM*4);
  bf16* hnk  = (bf16*)carve((size_t)MKP*HDIM*2);
  bf16* okb  = (bf16*)carve((size_t)MKP*HDIM*2);
  float* comb = (float*)carve((size_t)KEEPT*HDIM*4);
  float* rbuf = (float*)carve((size_t)KEEPT*4*4);
  float* qkvb = (float*)carve((size_t)8*3072*4);     // packed per-(e,l) qkv biases
  float* part = (float*)a1;                          // alias: 16*KEEPT*HDIM*4 = 15.7 MB <= 23 MB

  k_concat<<<4096, 256, 0, stream>>>(pose, scene, x);
  k_router<<<KEEPT, 64, 0, stream>>>(x, rf1w, rf1b, rf2w, rf2b, rbuf);
  k_pack_bias<<<96, 256, 0, stream>>>(wqb, wkb, wvb, qkvb);

  for (int e = 0; e < NE; e++) {
    for (int l = 0; l < NL; l++) {
      int el = e*NL + l;
      ConvArgs ca;
      ca.src[0] = wqw + (size_t)el*HDIM*HDIM;
      ca.src[1] = wkw + (size_t)el*HDIM*HDIM;
      ca.src[2] = wvw + (size_t)el*HDIM*HDIM;
      ca.src[3] = wow + (size_t)el*HDIM*HDIM;
      ca.src[4] = w1w + (size_t)el*HDIM*HFF;
      ca.src[5] = w3w + (size_t)el*HDIM*HFF;
      ca.src[6] = w2w + (size_t)el*HFF*HDIM;
      ca.dst[0] = qkvT;
      ca.dst[1] = qkvT + (size_t)1024*HDIM;
      ca.dst[2] = qkvT + (size_t)2048*HDIM;
      ca.dst[3] = woT;
      ca.dst[4] = w13T; ca.dst[5] = w13T; ca.dst[6] = w2T;
      k_convertT<<<12544, 256, 0, stream>>>(ca);

      const float* src_h = (l == 0) ? x : h;
      k_rmsnorm<<<TOK, 256, 0, stream>>>(src_h, anw + (size_t)el*HDIM, xn);
      // fused QKV GEMM: [4096,1024] @ [3072,1024]^T -> [4096,3072]
      k_gemm256<<<dim3(12, 16), 512, 0, stream>>>(xn, qkvT, qkvb + (size_t)el*3072, qkv3, 3072, HDIM, 0);
      k_vtrans<<<dim3(8, NHD, BATCH), 256, 0, stream>>>(qkv3 + 2048, vt, 3072);

      if (l == 0) {
        k_attn_mfma<<<dim3(8, NHD, BATCH), 256, 0, stream>>>(qkv3, qkv3 + 1024, vt, ob_, SEQ, SEQ, 3072);
        k_gemm<<<dim3(8, 32), 256, 0, stream>>>(ob_, woT, wob + (size_t)el*HDIM, x, nullptr, h, nullptr, HDIM, HDIM);
        k_rmsnorm<<<TOK, 256, 0, stream>>>(h, fnw + (size_t)el*HDIM, xn);
        // fused w1|w3 + SwiGLU: [4096,1024] @ [5632,1024]^T -> g [4096,2816]
        k_gemm256<<<dim3(22, 16), 512, 0, stream>>>(xn, w13T, nullptr, g, 2*HFF, HDIM, 1);
        k_gemm<<<dim3(8, 32), 256, 0, stream>>>(g, w2T, nullptr, h, nullptr, h, nullptr, HDIM, HFF);
      } else {
        k_attn_mfma<<<dim3(1, NHD, BATCH), 256, 0, stream>>>(qkv3, qkv3 + 1024, vt, okb, KEEP, KEEP, 3072);
        k_gather<<<1024, 256, 0, stream>>>(h, hk, okb);
        k_gemm<<<dim3(8, 2), 256, 0, stream>>>(okb, woT, wob + (size_t)el*HDIM, hk, nullptr, hk, nullptr, HDIM, HDIM);
        k_rmsnorm<<<MKP, 256, 0, stream>>>(hk, fnw + (size_t)el*HDIM, hnk);
        k_gemm256<<<dim3(22, 1), 512, 0, stream>>>(hnk, w13T, nullptr, g, 2*HFF, HDIM, 1);
        k_gemm<<<dim3(8, 2), 256, 0, stream>>>(g, w2T, nullptr, hk, nullptr, hk, nullptr, HDIM, HFF);
        k_accum<<<960, 256, 0, stream>>>(comb, hk, rbuf, e, (e == 0) ? 1 : 0);
      }
    }
  }
  k_proj<<<dim3(30, 16), 256, 0, stream>>>(comb, pw, part);
  k_ln<<<KEEPT, 256, 0, stream>>>(part, pb, lnw, lnb, out);
}

// Round 5
// 2787.068 us; speedup vs baseline: 1.3985x; 1.0168x over previous
//
#include <hip/hip_runtime.h>
#include <cstdint>
#include <cstddef>

#define HDIM 1024
#define NE 4
#define NL 2
#define NHD 16
#define SEQ 512
#define BATCH 8
#define HFF 2816
#define KEEP 30
#define KEEPT (BATCH*KEEP)  // 240
#define TOK (BATCH*SEQ)   // 4096
#define MKP 256           // padded keep-rows (240 -> 256)
#define EPSV 1e-5f

typedef __bf16 bf16;
typedef bf16 bf16x8 __attribute__((ext_vector_type(8)));
typedef bf16 bf16x4 __attribute__((ext_vector_type(4)));
typedef float f32x4 __attribute__((ext_vector_type(4)));

__device__ __forceinline__ void gll16(const bf16* g, bf16* l) {
  __builtin_amdgcn_global_load_lds((const __attribute__((address_space(1))) void*)g,
                                   (__attribute__((address_space(3))) void*)l, 16, 0, 0);
}

// bijective XCD-aware block remap (m204): correctness-neutral L2-locality swizzle
__device__ __forceinline__ int xcd_swz(int orig, int nwg) {
  int q = nwg >> 3, r = nwg & 7;
  int xcd = orig & 7, loc = orig >> 3;
  return (xcd < r ? xcd*(q+1) : r*(q+1) + (xcd-r)*q) + loc;
}

// ---------------- concat pose|scene -> x [TOK, HDIM] ----------------
__global__ __launch_bounds__(256) void k_concat(const float* __restrict__ pose,
                                                const float* __restrict__ scene,
                                                float* __restrict__ x) {
  int idx4 = blockIdx.x * 256 + threadIdx.x;     // over TOK*HDIM/4 = 1048576
  int tok = idx4 >> 8;                           // HDIM/4 = 256 vec4 per token
  int c = (idx4 & 255) << 2;
  int b = tok >> 9, s = tok & 511;
  const float* src = (s < 256) ? (pose + ((size_t)(b*256 + s)*HDIM + c))
                               : (scene + ((size_t)(b*256 + (s-256))*HDIM + c));
  *(f32x4*)(x + (size_t)tok*HDIM + c) = *(const f32x4*)src;
}

// ---------------- router (only the 240 kept tokens) ----------------
__global__ __launch_bounds__(64) void k_router(const float* __restrict__ x,
                                               const float* __restrict__ w1, const float* __restrict__ b1,
                                               const float* __restrict__ w2, const float* __restrict__ b2,
                                               float* __restrict__ r) {
  int row = blockIdx.x;                 // b*KEEP + s
  int b = row / KEEP, s = row - b*KEEP;
  int lane = threadIdx.x;
  const float* xr = x + (size_t)(b*SEQ + s)*HDIM;
  float p0=0.f, p1=0.f, p2=0.f, p3=0.f;
  for (int k2 = lane; k2 < HDIM; k2 += 64) {
    float xv = xr[k2];
    const float* wr = w1 + k2*4;
    p0 += xv*wr[0]; p1 += xv*wr[1]; p2 += xv*wr[2]; p3 += xv*wr[3];
  }
  #pragma unroll
  for (int off = 32; off; off >>= 1) {
    p0 += __shfl_xor(p0, off); p1 += __shfl_xor(p1, off);
    p2 += __shfl_xor(p2, off); p3 += __shfl_xor(p3, off);
  }
  if (lane == 0) {
    float gg[4] = {p0 + b1[0], p1 + b1[1], p2 + b1[2], p3 + b1[3]};
    #pragma unroll
    for (int i = 0; i < 4; i++) gg[i] = 0.5f*gg[i]*(1.f + erff(gg[i]*0.70710678f));
    float rr[4], sum = 0.f;
    #pragma unroll
    for (int i = 0; i < 4; i++) {
      float a = b2[i];
      #pragma unroll
      for (int j = 0; j < 4; j++) a += gg[j]*w2[j*4 + i];
      rr[i] = 1.f/(1.f + __expf(-a));
      sum += rr[i];
    }
    float inv = 1.f / fmaxf(sum, 1e-8f);
    #pragma unroll
    for (int i = 0; i < 4; i++) r[row*4 + i] = rr[i]*inv;
  }
}

// ---------------- RMSNorm: fp32 in -> bf16 out ----------------
__global__ __launch_bounds__(256) void k_rmsnorm(const float* __restrict__ in,
                                                 const float* __restrict__ w,
                                                 bf16* __restrict__ out) {
  int row = blockIdx.x, tid = threadIdx.x;
  const float* xr = in + (size_t)row*HDIM;
  f32x4 v = *(const f32x4*)(xr + tid*4);
  float ss = v[0]*v[0] + v[1]*v[1] + v[2]*v[2] + v[3]*v[3];
  #pragma unroll
  for (int off = 32; off; off >>= 1) ss += __shfl_xor(ss, off);
  __shared__ float part[4];
  if ((tid & 63) == 0) part[tid >> 6] = ss;
  __syncthreads();
  float scale = rsqrtf((part[0]+part[1]+part[2]+part[3]) * (1.f/HDIM) + EPSV);
  f32x4 wv = *(const f32x4*)(w + tid*4);
  bf16x4 o;
  #pragma unroll
  for (int i = 0; i < 4; i++) o[i] = (bf16)(v[i]*scale*wv[i]);
  *(bf16x4*)(out + (size_t)row*HDIM + tid*4) = o;
}

// ------------- per-(e,l) weight convert: fp32 [K,N] -> bf16 [N,K], 64x64 tiles -------------
// Vectorized: f32x4 loads, bf16x8 stores (was scalar 4B/2B). t=4 (w1) / t=5 (w3) write
// into ONE stacked buffer with 16-column interleave:
//   dest row for source col gr: (gr>>4)*32 + (t==5 ? 16 : 0) + (gr&15)
struct ConvArgs { const float* src[7]; bf16* dst[7]; };
__global__ __launch_bounds__(256) void k_convertT(ConvArgs a) {
  int id = blockIdx.x;   // 3136 64x64 tiles total: 4x256 sq + 704 w1 + 704 w3 + 704 w2
  int t, base;
  if (id < 1024)      { t = id >> 8; base = t << 8; }
  else if (id < 1728) { t = 4; base = 1024; }
  else if (id < 2432) { t = 5; base = 1728; }
  else                { t = 6; base = 2432; }
  int K = (t == 6) ? HFF : HDIM;
  int N = (t == 4 || t == 5) ? HFF : HDIM;
  int tl = id - base;
  int tilesN = N >> 6;
  int tk = tl / tilesN, tn = tl - tk*tilesN;
  __shared__ float tile[64][68];   // pad 68: 16B-aligned rows (272B)
  const float* src = a.src[t];
  bf16* dst = a.dst[t];
  int c4 = (threadIdx.x & 15) * 4;
  int r0 = threadIdx.x >> 4;
  #pragma unroll
  for (int i = 0; i < 4; i++) {
    int rr = r0 + i*16;
    *(f32x4*)&tile[rr][c4] = *(const f32x4*)&src[(size_t)(tk*64 + rr)*N + tn*64 + c4];
  }
  __syncthreads();
  int n = threadIdx.x >> 2;            // dst row within tile (= src col)
  int kb = (threadIdx.x & 3) * 16;     // 16 K-elems per thread
  int gr = tn*64 + n;
  size_t dr;
  if (t == 4)      dr = (size_t)((gr >> 4)*32 + (gr & 15));
  else if (t == 5) dr = (size_t)((gr >> 4)*32 + 16 + (gr & 15));
  else             dr = (size_t)gr;
  bf16* dp = dst + dr*K + tk*64 + kb;
  bf16x8 o0, o1;
  #pragma unroll
  for (int j = 0; j < 8; j++) { o0[j] = (bf16)tile[kb+j][n]; o1[j] = (bf16)tile[kb+8+j][n]; }
  *(bf16x8*)dp = o0;
  *(bf16x8*)(dp+8) = o1;
}

// ---------------- bias pack: qkvb[el][0:1024|1024:2048|2048:3072] = wqb|wkb|wvb ----------------
__global__ __launch_bounds__(256) void k_pack_bias(const float* __restrict__ qb, const float* __restrict__ kb,
                                                   const float* __restrict__ vb, float* __restrict__ dst) {
  int idx = blockIdx.x*256 + threadIdx.x;  // 8*3072 = 24576
  int el = idx / 3072, j = idx - el*3072;
  float v = (j < 1024) ? qb[el*1024 + j]
          : (j < 2048) ? kb[el*1024 + j - 1024]
                       : vb[el*1024 + j - 2048];
  dst[idx] = v;
}

// ===== LDS bank-swizzle (both GEMMs, proven R4: conflicts 4.3M -> 0) =========
//   stage: srcg = (lane&3) ^ ((lane>>3)&3)   read: swg = quad ^ ((l16>>1)&3)
// ===== 3-barrier split-stage K-loop (both GEMMs) =============================
// Per K-tile: {read pa0+pb; MFMA half0; BARRIER(1); stageB(kt+2); read pa1;
// MFMA half1; BARRIER(2); stageA(kt+2); vmcnt(4); BARRIER(3)}.
// Correctness: B[cur] reads all retire before BARRIER(1) (each ds_read's
// consuming MFMA waits lgkmcnt and issues before the barrier) -> stageB may
// overwrite after it. A[cur] likewise before BARRIER(2). vmcnt(4) at the
// boundary retires tile kt+1's 4 loads (per-wave); BARRIER(3) makes that
// global -> next iter may read buf[kt+1]. Pre-MFMA barriers removed (were
// schedule-alignment only, never a correctness dependency).
// ============================================================================

// ---------------- 128x128 bf16 MFMA GEMM, dbuf + counted vmcnt ----------------
// for wo / w2 / small l=1 GEMMs. 4 waves (2x2 of 64x64), BK=32, LDS 32 KB.
__global__ __launch_bounds__(256) void k_gemm(const bf16* __restrict__ A, const bf16* __restrict__ Bt,
    const float* __restrict__ bias, const float* __restrict__ resid, const bf16* __restrict__ siluSrc,
    float* __restrict__ outF, bf16* __restrict__ outB, int N, int K) {
  __shared__ __align__(16) bf16 As[2][128*32];
  __shared__ __align__(16) bf16 Bs[2][128*32];
  int tid = threadIdx.x;
  int wave = tid >> 6, lane = tid & 63;
  int quad = lane >> 4, l16 = lane & 15;
  int wm = (wave >> 1) * 64, wn = (wave & 1) * 64;
  int nwg = gridDim.x * gridDim.y;
  int wg = xcd_swz(blockIdx.y * gridDim.x + blockIdx.x, nwg);
  int bx = wg % gridDim.x, by = wg / gridDim.x;
  int m0 = by * 128, n0 = bx * 128;
  f32x4 zero4 = {0.f, 0.f, 0.f, 0.f};
  f32x4 acc[4][4];
  #pragma unroll
  for (int i = 0; i < 4; i++)
    #pragma unroll
    for (int j = 0; j < 4; j++) acc[i][j] = zero4;
  int srow = wave*32 + (lane >> 2);
  int sg = (lane & 3) ^ ((lane >> 3) & 3);
  int swg = quad ^ ((l16 >> 1) & 3);
  const bf16* Ap = A + (size_t)(m0 + srow)*K + sg*8;
  const bf16* Bp = Bt + (size_t)(n0 + srow)*K + sg*8;
  auto stageA = [&](int buf, int kt) {
    gll16(Ap + (size_t)kt*32,                &As[buf][wave*1024]);
    gll16(Ap + (size_t)kt*32 + (size_t)16*K, &As[buf][wave*1024 + 512]);
  };
  auto stageB = [&](int buf, int kt) {
    gll16(Bp + (size_t)kt*32,                &Bs[buf][wave*1024]);
    gll16(Bp + (size_t)kt*32 + (size_t)16*K, &Bs[buf][wave*1024 + 512]);
  };
  int NT = K >> 5;
  stageA(0, 0); stageB(0, 0);
  stageA(1, 1); stageB(1, 1);
  asm volatile("s_waitcnt vmcnt(4)" ::: "memory");
  asm volatile("s_barrier" ::: "memory");
  for (int kt = 0; kt < NT; ++kt) {
    int cur = kt & 1;
    bf16x8 pb[4], pa[2];
    #pragma unroll
    for (int i = 0; i < 4; i++) pb[i] = *(const bf16x8*)&Bs[cur][(wn + i*16 + l16)*32 + swg*8];
    #pragma unroll
    for (int i = 0; i < 2; i++) pa[i] = *(const bf16x8*)&As[cur][(wm + i*16 + l16)*32 + swg*8];
    __builtin_amdgcn_s_setprio(1);
    #pragma unroll
    for (int mi = 0; mi < 2; mi++)
      #pragma unroll
      for (int ni = 0; ni < 4; ni++)
        acc[mi][ni] = __builtin_amdgcn_mfma_f32_16x16x32_bf16(pa[mi], pb[ni], acc[mi][ni], 0, 0, 0);
    __builtin_amdgcn_s_setprio(0);
    asm volatile("s_barrier" ::: "memory");          // B[cur] + A-half0 consumed
    if (kt + 2 < NT) stageB(cur, kt + 2);
    bf16x8 pa2[2];
    #pragma unroll
    for (int i = 0; i < 2; i++) pa2[i] = *(const bf16x8*)&As[cur][(wm + 32 + i*16 + l16)*32 + swg*8];
    __builtin_amdgcn_s_setprio(1);
    #pragma unroll
    for (int mi = 0; mi < 2; mi++)
      #pragma unroll
      for (int ni = 0; ni < 4; ni++)
        acc[2+mi][ni] = __builtin_amdgcn_mfma_f32_16x16x32_bf16(pa2[mi], pb[ni], acc[2+mi][ni], 0, 0, 0);
    __builtin_amdgcn_s_setprio(0);
    asm volatile("s_barrier" ::: "memory");          // A[cur] fully consumed
    if (kt + 2 < NT) stageA(cur, kt + 2);
    if (kt + 1 < NT) {
      if (kt + 2 < NT) asm volatile("s_waitcnt vmcnt(4)" ::: "memory");
      else             asm volatile("s_waitcnt vmcnt(0)" ::: "memory");
      asm volatile("s_barrier" ::: "memory");        // tile kt+1 landed globally
    }
  }
  #pragma unroll
  for (int mi = 0; mi < 4; mi++) {
    #pragma unroll
    for (int ni = 0; ni < 4; ni++) {
      int colg = n0 + wn + ni*16 + l16;
      float bv = bias ? bias[colg] : 0.f;
      #pragma unroll
      for (int rr = 0; rr < 4; rr++) {
        int rowg = m0 + wm + mi*16 + quad*4 + rr;
        size_t off = (size_t)rowg*N + colg;
        float vv = acc[mi][ni][rr] + bv;
        if (resid) vv += resid[off];
        if (siluSrc) { float a = (float)siluSrc[off]; vv *= a / (1.f + __expf(-a)); }
        if (outF) outF[off] = vv;
        else      outB[off] = (bf16)vv;
      }
    }
  }
}

// ---------------- 256x256 counted-vmcnt GEMM (3-barrier split-stage) ----------------
// 512 thr = 8 waves (2M x 4N), per-wave C = 128x64 (acc[8][4]); BK=32, LDS dbuf 64 KB.
// swiglu=1: Bt is 16-col-interleaved w1|w3; epilogue writes g = silu(a1)*a3, stride N/2.
__global__ __launch_bounds__(512, 2) void k_gemm256(const bf16* __restrict__ A, const bf16* __restrict__ Bt,
    const float* __restrict__ bias, bf16* __restrict__ out, int N, int K, int swiglu) {
  __shared__ __align__(16) bf16 As[2][256*32];
  __shared__ __align__(16) bf16 Bs[2][256*32];
  int tid = threadIdx.x;
  int wave = tid >> 6, lane = tid & 63;
  int quad = lane >> 4, l16 = lane & 15;
  int wm128 = (wave >> 2) * 128;       // 2 waves in M
  int wn64  = (wave & 3) * 64;         // 4 waves in N
  int nwg = gridDim.x * gridDim.y;
  int wg = xcd_swz(blockIdx.y * gridDim.x + blockIdx.x, nwg);
  int bx = wg % gridDim.x, by = wg / gridDim.x;
  int m0 = by * 256, n0 = bx * 256;
  int NT = K >> 5;
  f32x4 z = {0.f, 0.f, 0.f, 0.f};
  f32x4 acc[8][4];
  #pragma unroll
  for (int i = 0; i < 8; i++)
    #pragma unroll
    for (int j = 0; j < 4; j++) acc[i][j] = z;
  int sg = (lane & 3) ^ ((lane >> 3) & 3);
  int swg = quad ^ ((l16 >> 1) & 3);
  const bf16* aSrc = A + (size_t)(m0 + wave*16 + (lane>>2))*K + sg*8;
  const bf16* bSrc = Bt + (size_t)(n0 + wave*16 + (lane>>2))*K + sg*8;
  auto stageA = [&](int buf, int kt) {
    #pragma unroll
    for (int r = 0; r < 2; r++)
      gll16(aSrc + (size_t)(r*128)*K + (size_t)kt*32, &As[buf][(r*128 + wave*16)*32]);
  };
  auto stageB = [&](int buf, int kt) {
    #pragma unroll
    for (int r = 0; r < 2; r++)
      gll16(bSrc + (size_t)(r*128)*K + (size_t)kt*32, &Bs[buf][(r*128 + wave*16)*32]);
  };
  stageA(0, 0); stageB(0, 0);
  stageA(1, 1); stageB(1, 1);
  asm volatile("s_waitcnt vmcnt(4)" ::: "memory");
  asm volatile("s_barrier" ::: "memory");
  for (int kt = 0; kt < NT; ++kt) {
    int cur = kt & 1;
    bf16x8 pb[4], pa[4];
    #pragma unroll
    for (int i = 0; i < 4; i++)
      pa[i] = *(const bf16x8*)&As[cur][(wm128 + i*16 + l16)*32 + swg*8];
    #pragma unroll
    for (int i = 0; i < 4; i++)
      pb[i] = *(const bf16x8*)&Bs[cur][(wn64 + i*16 + l16)*32 + swg*8];
    __builtin_amdgcn_s_setprio(1);
    #pragma unroll
    for (int mi = 0; mi < 4; mi++)
      #pragma unroll
      for (int ni = 0; ni < 4; ni++)
        acc[mi][ni] = __builtin_amdgcn_mfma_f32_16x16x32_bf16(pa[mi], pb[ni], acc[mi][ni], 0, 0, 0);
    __builtin_amdgcn_s_setprio(0);
    asm volatile("s_barrier" ::: "memory");          // B[cur] + A rows 0..63 consumed
    if (kt + 2 < NT) stageB(cur, kt + 2);
    bf16x8 pa2[4];
    #pragma unroll
    for (int i = 0; i < 4; i++)
      pa2[i] = *(const bf16x8*)&As[cur][(wm128 + 64 + i*16 + l16)*32 + swg*8];
    __builtin_amdgcn_s_setprio(1);
    #pragma unroll
    for (int mi = 0; mi < 4; mi++)
      #pragma unroll
      for (int ni = 0; ni < 4; ni++)
        acc[4+mi][ni] = __builtin_amdgcn_mfma_f32_16x16x32_bf16(pa2[mi], pb[ni], acc[4+mi][ni], 0, 0, 0);
    __builtin_amdgcn_s_setprio(0);
    asm volatile("s_barrier" ::: "memory");          // A[cur] fully consumed
    if (kt + 2 < NT) stageA(cur, kt + 2);
    if (kt + 1 < NT) {
      if (kt + 2 < NT) asm volatile("s_waitcnt vmcnt(4)" ::: "memory");
      else             asm volatile("s_waitcnt vmcnt(0)" ::: "memory");
      asm volatile("s_barrier" ::: "memory");        // tile kt+1 landed globally
    }
  }
  // ---- epilogue (proven C layout: row = quad*4+rr, col = l16) ----
  if (!swiglu) {
    #pragma unroll
    for (int ni = 0; ni < 4; ni++) {
      int colg = n0 + wn64 + ni*16 + l16;
      float bv = bias ? bias[colg] : 0.f;
      #pragma unroll
      for (int mi = 0; mi < 8; mi++)
        #pragma unroll
        for (int rr = 0; rr < 4; rr++) {
          int rowg = m0 + wm128 + mi*16 + quad*4 + rr;
          out[(size_t)rowg*N + colg] = (bf16)(acc[mi][ni][rr] + bv);
        }
    }
  } else {
    int half = N >> 1;
    #pragma unroll
    for (int np = 0; np < 2; np++) {
      int colo = ((n0 + wn64) >> 1) + np*16 + l16;
      #pragma unroll
      for (int mi = 0; mi < 8; mi++)
        #pragma unroll
        for (int rr = 0; rr < 4; rr++) {
          int rowg = m0 + wm128 + mi*16 + quad*4 + rr;
          float xv = acc[mi][np*2][rr];
          float yv = acc[mi][np*2+1][rr];
          out[(size_t)rowg*half + colo] = (bf16)(xv / (1.f + __expf(-xv)) * yv);
        }
    }
  }
}

// ---------------- V transpose: vt[b][h][d][s] = v[(b*SEQ+s)*vs + h*64+d] ----------------
__global__ __launch_bounds__(256) void k_vtrans(const bf16* __restrict__ v, bf16* __restrict__ vt, int vs) {
  __shared__ bf16 t[64][72];
  int b = blockIdx.z, h = blockIdx.y, s0 = blockIdx.x * 64;
  int r = threadIdx.x >> 2, c0 = (threadIdx.x & 3) * 16;
  const bf16* vp = v + (size_t)(b*SEQ + s0 + r)*vs + h*64 + c0;
  bf16x8 v0 = *(const bf16x8*)vp;
  bf16x8 v1 = *(const bf16x8*)(vp + 8);
  #pragma unroll
  for (int j = 0; j < 8; j++) { t[r][c0+j] = v0[j]; t[r][c0+8+j] = v1[j]; }
  __syncthreads();
  bf16x8 o0, o1;
  #pragma unroll
  for (int j = 0; j < 8; j++) { o0[j] = t[c0+j][r]; o1[j] = t[c0+8+j][r]; }
  bf16* op = vt + ((size_t)(b*NHD + h)*64 + r)*512 + s0 + c0;
  *(bf16x8*)op = o0;
  *(bf16x8*)(op + 8) = o1;
}

// ---------------- MFMA attention ----------------
// ALL loops touching acc[32] are FULLY unrolled — partial unroll demotes the
// 128-VGPR accumulator array to scratch (R1: 765 MB HBM spill traffic/dispatch).
__global__ __launch_bounds__(256, 1) void k_attn_mfma(const bf16* __restrict__ q,
    const bf16* __restrict__ k, const bf16* __restrict__ vt,
    bf16* __restrict__ o, int qlen, int orb, int qs) {
  __shared__ bf16 Ps[4][16][520];   // pad 8 keeps ds_read_b128 16B-aligned, 2-way row alias
  int tid = threadIdx.x;
  int wave = tid >> 6, lane = tid & 63;
  int quad = lane >> 4, l16 = lane & 15;
  int b = blockIdx.z, head = blockIdx.y;
  int q0 = blockIdx.x * 64 + wave * 16;

  const bf16* qp = q + (size_t)(b*SEQ + q0 + l16)*qs + head*64 + quad*8;
  bf16x8 aq0 = *(const bf16x8*)(qp);
  bf16x8 aq1 = *(const bf16x8*)(qp + 32);

  f32x4 z = {0.f, 0.f, 0.f, 0.f};
  f32x4 acc[32];
  #pragma unroll
  for (int ni = 0; ni < 32; ni++) acc[ni] = z;
  const bf16* kb = k + (size_t)(b*SEQ + l16)*qs + head*64 + quad*8;
  #pragma unroll
  for (int ni = 0; ni < 32; ni++) {
    const bf16* kp = kb + (size_t)(ni*16)*qs;
    bf16x8 b0 = *(const bf16x8*)(kp);
    bf16x8 b1 = *(const bf16x8*)(kp + 32);
    acc[ni] = __builtin_amdgcn_mfma_f32_16x16x32_bf16(aq0, b0, acc[ni], 0, 0, 0);
    acc[ni] = __builtin_amdgcn_mfma_f32_16x16x32_bf16(aq1, b1, acc[ni], 0, 0, 0);
  }
  float mx[4] = {-3e30f, -3e30f, -3e30f, -3e30f};
  #pragma unroll
  for (int ni = 0; ni < 32; ni++)
    #pragma unroll
    for (int rr = 0; rr < 4; rr++) {
      float s = acc[ni][rr] * 0.125f;
      acc[ni][rr] = s;
      mx[rr] = fmaxf(mx[rr], s);
    }
  #pragma unroll
  for (int off = 1; off <= 8; off <<= 1)
    #pragma unroll
    for (int rr = 0; rr < 4; rr++)
      mx[rr] = fmaxf(mx[rr], __shfl_xor(mx[rr], off));
  float sm[4] = {0.f, 0.f, 0.f, 0.f};
  #pragma unroll
  for (int ni = 0; ni < 32; ni++)
    #pragma unroll
    for (int rr = 0; rr < 4; rr++) {
      float p = __expf(acc[ni][rr] - mx[rr]);
      acc[ni][rr] = p;
      sm[rr] += p;
    }
  #pragma unroll
  for (int off = 1; off <= 8; off <<= 1)
    #pragma unroll
    for (int rr = 0; rr < 4; rr++)
      sm[rr] += __shfl_xor(sm[rr], off);
  #pragma unroll
  for (int ni = 0; ni < 32; ni++)
    #pragma unroll
    for (int rr = 0; rr < 4; rr++)
      Ps[wave][quad*4 + rr][ni*16 + l16] = (bf16)acc[ni][rr];
  const bf16* vtb = vt + ((size_t)(b*NHD + head)*64 + l16)*512 + quad*8;
  f32x4 accO[4] = {z, z, z, z};
  #pragma unroll 4
  for (int kk = 0; kk < 16; kk++) {
    bf16x8 ap = *(const bf16x8*)&Ps[wave][l16][kk*32 + quad*8];
    #pragma unroll
    for (int ni = 0; ni < 4; ni++) {
      bf16x8 bv = *(const bf16x8*)(vtb + (size_t)(ni*16)*512 + kk*32);
      accO[ni] = __builtin_amdgcn_mfma_f32_16x16x32_bf16(ap, bv, accO[ni], 0, 0, 0);
    }
  }
  float inv[4];
  #pragma unroll
  for (int rr = 0; rr < 4; rr++) inv[rr] = 1.f / sm[rr];
  #pragma unroll
  for (int ni = 0; ni < 4; ni++)
    #pragma unroll
    for (int rr = 0; rr < 4; rr++) {
      int row = q0 + quad*4 + rr;
      if (row < qlen)
        o[(size_t)(b*orb + row)*HDIM + head*64 + ni*16 + l16] = (bf16)(accO[ni][rr] * inv[rr]);
    }
}

// ---------------- gather kept rows of h -> hk (zero-pad 240..255), zero ok pad ----------------
__global__ __launch_bounds__(256) void k_gather(const float* __restrict__ h,
                                                float* __restrict__ hk, bf16* __restrict__ ok) {
  int idx = blockIdx.x*256 + threadIdx.x;    // 256*1024 = 262144
  int row = idx >> 10, col = idx & 1023;
  if (row < BATCH*KEEP) {
    int b = row / KEEP, s = row - b*KEEP;
    hk[idx] = h[(size_t)(b*SEQ + s)*HDIM + col];
  } else {
    hk[idx] = 0.f;
    ok[idx] = (bf16)0.f;
  }
}

// ---------------- combined += hk * r[:,e] ----------------
__global__ __launch_bounds__(256) void k_accum(float* __restrict__ comb, const float* __restrict__ hk,
                                               const float* __restrict__ r, int e, int first) {
  int idx = blockIdx.x*256 + threadIdx.x;    // 240*1024 = 245760
  int row = idx >> 10;
  float vv = hk[idx] * r[row*4 + e];
  comb[idx] = (first ? 0.f : comb[idx]) + vv;
}

// ---------------- final proj, split-K x16 with 8-row weight reuse ----------------
__global__ __launch_bounds__(256) void k_proj(const float* __restrict__ comb,
                                              const float* __restrict__ pw,
                                              float* __restrict__ part) {
  int rg = blockIdx.x, ks = blockIdx.y, tid = threadIdx.x;
  __shared__ float xr[8][64];
  for (int i = tid; i < 8*64; i += 256) {
    int r = i >> 6, kk = i & 63;
    xr[r][kk] = comb[(size_t)(rg*8 + r)*HDIM + ks*64 + kk];
  }
  __syncthreads();
  f32x4 acc[8];
  #pragma unroll
  for (int r = 0; r < 8; r++) acc[r] = (f32x4){0.f,0.f,0.f,0.f};
  const float* wp = pw + (size_t)(ks*64)*HDIM + tid*4;
  #pragma unroll 4
  for (int kk = 0; kk < 64; kk++) {
    f32x4 w4 = *(const f32x4*)(wp + (size_t)kk*HDIM);
    #pragma unroll
    for (int r = 0; r < 8; r++) acc[r] += xr[r][kk] * w4;
  }
  #pragma unroll
  for (int r = 0; r < 8; r++)
    *(f32x4*)(part + ((size_t)ks*KEEPT + rg*8 + r)*HDIM + tid*4) = acc[r];
}

__global__ __launch_bounds__(256) void k_ln(const float* __restrict__ part, const float* __restrict__ pb,
    const float* __restrict__ lnw, const float* __restrict__ lnb, float* __restrict__ out) {
  int row = blockIdx.x, tid = threadIdx.x;
  f32x4 acc = *(const f32x4*)(pb + tid*4);
  #pragma unroll
  for (int s = 0; s < 16; s++)
    acc += *(const f32x4*)(part + ((size_t)s*KEEPT + row)*HDIM + tid*4);
  float ps = acc[0]+acc[1]+acc[2]+acc[3];
  #pragma unroll
  for (int off = 32; off; off >>= 1) ps += __shfl_xor(ps, off);
  __shared__ float red1[4], red2[4];
  if ((tid & 63) == 0) red1[tid >> 6] = ps;
  __syncthreads();
  float mu = (red1[0]+red1[1]+red1[2]+red1[3]) * (1.f/HDIM);
  f32x4 d;
  #pragma unroll
  for (int i = 0; i < 4; i++) d[i] = acc[i] - mu;
  float pv = d[0]*d[0]+d[1]*d[1]+d[2]*d[2]+d[3]*d[3];
  #pragma unroll
  for (int off = 32; off; off >>= 1) pv += __shfl_xor(pv, off);
  if ((tid & 63) == 0) red2[tid >> 6] = pv;
  __syncthreads();
  float rs = rsqrtf((red2[0]+red2[1]+red2[2]+red2[3]) * (1.f/HDIM) + EPSV);
  f32x4 lw = *(const f32x4*)(lnw + tid*4);
  f32x4 lb = *(const f32x4*)(lnb + tid*4);
  f32x4 o;
  #pragma unroll
  for (int i = 0; i < 4; i++) o[i] = d[i]*rs*lw[i] + lb[i];
  *(f32x4*)(out + (size_t)row*HDIM + tid*4) = o;
}

extern "C" void kernel_launch(void* const* d_in, const int* in_sizes, int n_in,
                              void* d_out, int out_size, void* d_ws, size_t ws_size,
                              hipStream_t stream) {
  (void)in_sizes; (void)n_in; (void)out_size; (void)ws_size;
  const float* pose = (const float*)d_in[0];
  const float* scene = (const float*)d_in[1];
  const float* rf1w = (const float*)d_in[2];
  const float* rf1b = (const float*)d_in[3];
  const float* rf2w = (const float*)d_in[4];
  const float* rf2b = (const float*)d_in[5];
  const float* anw = (const float*)d_in[6];
  const float* wqw = (const float*)d_in[7];
  const float* wqb = (const float*)d_in[8];
  const float* wkw = (const float*)d_in[9];
  const float* wkb = (const float*)d_in[10];
  const float* wvw = (const float*)d_in[11];
  const float* wvb = (const float*)d_in[12];
  const float* wow = (const float*)d_in[13];
  const float* wob = (const float*)d_in[14];
  const float* fnw = (const float*)d_in[15];
  const float* w1w = (const float*)d_in[16];
  const float* w2w = (const float*)d_in[17];
  const float* w3w = (const float*)d_in[18];
  const float* pw  = (const float*)d_in[19];
  const float* pb  = (const float*)d_in[20];
  const float* lnw = (const float*)d_in[21];
  const float* lnb = (const float*)d_in[22];
  float* out = (float*)d_out;

  char* p = (char*)d_ws;
  auto carve = [&](size_t bytes) { void* r = (void*)p; p += (bytes + 255) & ~(size_t)255; return r; };
  float* x   = (float*)carve((size_t)TOK*HDIM*4);
  float* h   = (float*)carve((size_t)TOK*HDIM*4);
  bf16* xn   = (bf16*)carve((size_t)TOK*HDIM*2);
  bf16* qkv3 = (bf16*)carve((size_t)TOK*3072*2);     // fused Q|K|V, row stride 3072
  bf16* ob_  = (bf16*)carve((size_t)TOK*HDIM*2);
  bf16* vt   = (bf16*)carve((size_t)TOK*HDIM*2);     // vt[b][h][64][512]
  bf16* a1   = (bf16*)carve((size_t)TOK*HFF*2);      // reserved (part alias)
  bf16* g    = (bf16*)carve((size_t)TOK*HFF*2);
  bf16* qkvT = (bf16*)carve((size_t)3072*HDIM*2);    // stacked wq^T|wk^T|wv^T [3072][1024]
  bf16* woT  = (bf16*)carve((size_t)HDIM*HDIM*2);
  bf16* w13T = (bf16*)carve((size_t)2*HDIM*HFF*2);   // interleaved w1^T|w3^T [5632][1024]
  bf16* w2T  = (bf16*)carve((size_t)HFF*HDIM*2);
  float* hk  = (float*)carve((size_t)MKP*HDIM*4);
  bf16* hnk  = (bf16*)carve((size_t)MKP*HDIM*2);
  bf16* okb  = (bf16*)carve((size_t)MKP*HDIM*2);
  float* comb = (float*)carve((size_t)KEEPT*HDIM*4);
  float* rbuf = (float*)carve((size_t)KEEPT*4*4);
  float* qkvb = (float*)carve((size_t)8*3072*4);     // packed per-(e,l) qkv biases
  float* part = (float*)a1;                          // alias: 16*KEEPT*HDIM*4 = 15.7 MB <= 23 MB

  k_concat<<<4096, 256, 0, stream>>>(pose, scene, x);
  k_router<<<KEEPT, 64, 0, stream>>>(x, rf1w, rf1b, rf2w, rf2b, rbuf);
  k_pack_bias<<<96, 256, 0, stream>>>(wqb, wkb, wvb, qkvb);

  for (int e = 0; e < NE; e++) {
    for (int l = 0; l < NL; l++) {
      int el = e*NL + l;
      ConvArgs ca;
      ca.src[0] = wqw + (size_t)el*HDIM*HDIM;
      ca.src[1] = wkw + (size_t)el*HDIM*HDIM;
      ca.src[2] = wvw + (size_t)el*HDIM*HDIM;
      ca.src[3] = wow + (size_t)el*HDIM*HDIM;
      ca.src[4] = w1w + (size_t)el*HDIM*HFF;
      ca.src[5] = w3w + (size_t)el*HDIM*HFF;
      ca.src[6] = w2w + (size_t)el*HFF*HDIM;
      ca.dst[0] = qkvT;
      ca.dst[1] = qkvT + (size_t)1024*HDIM;
      ca.dst[2] = qkvT + (size_t)2048*HDIM;
      ca.dst[3] = woT;
      ca.dst[4] = w13T; ca.dst[5] = w13T; ca.dst[6] = w2T;
      k_convertT<<<3136, 256, 0, stream>>>(ca);

      const float* src_h = (l == 0) ? x : h;
      k_rmsnorm<<<TOK, 256, 0, stream>>>(src_h, anw + (size_t)el*HDIM, xn);
      // fused QKV GEMM: [4096,1024] @ [3072,1024]^T -> [4096,3072]
      k_gemm256<<<dim3(12, 16), 512, 0, stream>>>(xn, qkvT, qkvb + (size_t)el*3072, qkv3, 3072, HDIM, 0);
      k_vtrans<<<dim3(8, NHD, BATCH), 256, 0, stream>>>(qkv3 + 2048, vt, 3072);

      if (l == 0) {
        k_attn_mfma<<<dim3(8, NHD, BATCH), 256, 0, stream>>>(qkv3, qkv3 + 1024, vt, ob_, SEQ, SEQ, 3072);
        k_gemm<<<dim3(8, 32), 256, 0, stream>>>(ob_, woT, wob + (size_t)el*HDIM, x, nullptr, h, nullptr, HDIM, HDIM);
        k_rmsnorm<<<TOK, 256, 0, stream>>>(h, fnw + (size_t)el*HDIM, xn);
        // fused w1|w3 + SwiGLU: [4096,1024] @ [5632,1024]^T -> g [4096,2816]
        k_gemm256<<<dim3(22, 16), 512, 0, stream>>>(xn, w13T, nullptr, g, 2*HFF, HDIM, 1);
        k_gemm<<<dim3(8, 32), 256, 0, stream>>>(g, w2T, nullptr, h, nullptr, h, nullptr, HDIM, HFF);
      } else {
        k_attn_mfma<<<dim3(1, NHD, BATCH), 256, 0, stream>>>(qkv3, qkv3 + 1024, vt, okb, KEEP, KEEP, 3072);
        k_gather<<<1024, 256, 0, stream>>>(h, hk, okb);
        k_gemm<<<dim3(8, 2), 256, 0, stream>>>(okb, woT, wob + (size_t)el*HDIM, hk, nullptr, hk, nullptr, HDIM, HDIM);
        k_rmsnorm<<<MKP, 256, 0, stream>>>(hk, fnw + (size_t)el*HDIM, hnk);
        k_gemm256<<<dim3(22, 1), 512, 0, stream>>>(hnk, w13T, nullptr, g, 2*HFF, HDIM, 1);
        k_gemm<<<dim3(8, 2), 256, 0, stream>>>(g, w2T, nullptr, hk, nullptr, hk, nullptr, HDIM, HFF);
        k_accum<<<960, 256, 0, stream>>>(comb, hk, rbuf, e, (e == 0) ? 1 : 0);
      }
    }
  }
  k_proj<<<dim3(30, 16), 256, 0, stream>>>(comb, pw, part);
  k_ln<<<KEEPT, 256, 0, stream>>>(part, pb, lnw, lnb, out);
}